// Round 2
// baseline (703.656 us; speedup 1.0000x reference)
//
#include <hip/hip_runtime.h>
#include <math.h>

#define H 8
#define DM 512
#define DK 64
#define LQ 1024
#define LK 2048
#define BATCH 4
#define LN_EPS 1e-5f

// ---------------------------------------------------------------------------
// GEMM: C[M][512] = A[M][512] * W[N=512][K=512]^T + bias (+ optional residual)
// W row-major [out_feature][in_feature] -> C[m][n] = sum_k A[m][k]*W[n][k]
// Tile: BM=64 x BN=128, BK=32. 256 threads, each computes 4x8.
// Column split: thread covers cols {tx*4..+3} and {64+tx*4..+3} so LDS reads
// are 2-way (free, m136) instead of 4-way bank conflicts.
// ---------------------------------------------------------------------------
#define BM 64
#define BN 128
#define BK 32

__global__ __launch_bounds__(256) void gemm_bt(const float* __restrict__ A,
                                               const float* __restrict__ W,
                                               const float* __restrict__ bias,
                                               const float* __restrict__ resid,
                                               float* __restrict__ C)
{
    __shared__ float As[BK][BM + 4];   // [kk][row]
    __shared__ float Bs[BK][BN + 4];   // [kk][col]
    const int tid = threadIdx.x;
    const int tx = tid & 15;          // 0..15 -> column groups
    const int ty = tid >> 4;          // 0..15 -> row groups
    const long m0 = (long)blockIdx.y * BM;
    const int  n0 = blockIdx.x * BN;

    float acc[4][8];
#pragma unroll
    for (int i = 0; i < 4; ++i)
#pragma unroll
        for (int j = 0; j < 8; ++j) acc[i][j] = 0.f;

    for (int k0 = 0; k0 < DM; k0 += BK) {
        // stage A tile (64x32): 2 float4 per thread
#pragma unroll
        for (int t = 0; t < 2; ++t) {
            int i = t * 256 + tid;
            int r = i >> 3, c = (i & 7) * 4;
            float4 v = *(const float4*)(A + (m0 + r) * DM + k0 + c);
            As[c + 0][r] = v.x; As[c + 1][r] = v.y;
            As[c + 2][r] = v.z; As[c + 3][r] = v.w;
        }
        // stage W tile (128x32): 4 float4 per thread
#pragma unroll
        for (int t = 0; t < 4; ++t) {
            int i = t * 256 + tid;
            int r = i >> 3, c = (i & 7) * 4;
            float4 v = *(const float4*)(W + (long)(n0 + r) * DM + k0 + c);
            Bs[c + 0][r] = v.x; Bs[c + 1][r] = v.y;
            Bs[c + 2][r] = v.z; Bs[c + 3][r] = v.w;
        }
        __syncthreads();
#pragma unroll 8
        for (int kk = 0; kk < BK; ++kk) {
            float4 a4 = *(const float4*)&As[kk][ty * 4];
            float4 b0 = *(const float4*)&Bs[kk][tx * 4];
            float4 b1 = *(const float4*)&Bs[kk][64 + tx * 4];
            float a[4] = {a4.x, a4.y, a4.z, a4.w};
            float b[8] = {b0.x, b0.y, b0.z, b0.w, b1.x, b1.y, b1.z, b1.w};
#pragma unroll
            for (int i = 0; i < 4; ++i)
#pragma unroll
                for (int j = 0; j < 8; ++j) acc[i][j] += a[i] * b[j];
        }
        __syncthreads();
    }

    // epilogue
    float4 blo = *(const float4*)(bias + n0 + tx * 4);
    float4 bhi = *(const float4*)(bias + n0 + 64 + tx * 4);
#pragma unroll
    for (int i = 0; i < 4; ++i) {
        long row = m0 + ty * 4 + i;
        float4 o0 = make_float4(acc[i][0] + blo.x, acc[i][1] + blo.y,
                                acc[i][2] + blo.z, acc[i][3] + blo.w);
        float4 o1 = make_float4(acc[i][4] + bhi.x, acc[i][5] + bhi.y,
                                acc[i][6] + bhi.z, acc[i][7] + bhi.w);
        if (resid) {
            float4 r0 = *(const float4*)(resid + row * DM + n0 + tx * 4);
            float4 r1 = *(const float4*)(resid + row * DM + n0 + 64 + tx * 4);
            o0.x += r0.x; o0.y += r0.y; o0.z += r0.z; o0.w += r0.w;
            o1.x += r1.x; o1.y += r1.y; o1.z += r1.z; o1.w += r1.w;
        }
        *(float4*)(C + row * DM + n0 + tx * 4) = o0;
        *(float4*)(C + row * DM + n0 + 64 + tx * 4) = o1;
    }
}

// ---------------------------------------------------------------------------
// Flash attention, fp32. One block = one (b,h) x 64 q-rows. 256 threads:
// thread t owns q-row (t>>2), column-group (t&3) of 16 within each 64-wide
// k-tile, and d-chunk (t&3)*16 of the output. Online softmax; PV via __shfl
// broadcast of P within the 4-lane quad (no P LDS round-trip).
// 1/sqrt(dk)=0.125 is folded into the staged q tile.
// ---------------------------------------------------------------------------
__global__ __launch_bounds__(256) void attn_kernel(const float* __restrict__ q,
                                                   const float* __restrict__ k,
                                                   const float* __restrict__ v,
                                                   const int* __restrict__ mask,
                                                   float* __restrict__ o)
{
    __shared__ float qs[64][68];   // [row][d]   (pre-scaled by 0.125)
    __shared__ float kts[64][68];  // [d][c]  (transposed)
    __shared__ float vs[64][68];   // [c][d]
    __shared__ float ms[64];       // additive mask for this k-tile

    const int tid = threadIdx.x;
    const int cg  = tid & 3;
    const int row = tid >> 2;
    const int bh  = blockIdx.y;
    const int b   = bh >> 3, h = bh & 7;
    const int q0  = blockIdx.x * 64;

    const float* qbase = q + ((long)(b * LQ + q0)) * DM + h * DK;
    const float* kbase = k + ((long)b * LK) * DM + h * DK;
    const float* vbase = v + ((long)b * LK) * DM + h * DK;

    // stage q tile (64 rows x 64 dims), fold in softmax scale
#pragma unroll
    for (int t = 0; t < 4; ++t) {
        int i = t * 256 + tid;
        int r = i >> 4, c = (i & 15) * 4;
        float4 val = *(const float4*)(qbase + (long)r * DM + c);
        val.x *= 0.125f; val.y *= 0.125f; val.z *= 0.125f; val.w *= 0.125f;
        *(float4*)&qs[r][c] = val;
    }

    float m_run = -1e30f, l_run = 0.f;
    float o_acc[16];
#pragma unroll
    for (int j = 0; j < 16; ++j) o_acc[j] = 0.f;

    const int base_lane = (tid & 63) & ~3;

    for (int kt = 0; kt < LK; kt += 64) {
        __syncthreads();   // protect previous tile's LDS from overwrite
        // stage k (transposed) and v tiles
#pragma unroll
        for (int t = 0; t < 4; ++t) {
            int i = t * 256 + tid;
            int c = i >> 4, dq = (i & 15) * 4;
            float4 kv = *(const float4*)(kbase + (long)(kt + c) * DM + dq);
            kts[dq + 0][c] = kv.x; kts[dq + 1][c] = kv.y;
            kts[dq + 2][c] = kv.z; kts[dq + 3][c] = kv.w;
            float4 vv = *(const float4*)(vbase + (long)(kt + c) * DM + dq);
            *(float4*)&vs[c][dq] = vv;
        }
        if (tid < 64) ms[tid] = mask[b * LK + kt + tid] ? 0.f : -1e30f;
        __syncthreads();

        // S = q . k^T for my 16 columns
        float s[16];
#pragma unroll
        for (int j = 0; j < 16; ++j) s[j] = 0.f;
#pragma unroll 4
        for (int kk = 0; kk < 64; ++kk) {
            float qv = qs[row][kk];
            const float4* kp = (const float4*)&kts[kk][cg * 16];
            float4 k0v = kp[0], k1v = kp[1], k2v = kp[2], k3v = kp[3];
            float kv[16] = {k0v.x, k0v.y, k0v.z, k0v.w, k1v.x, k1v.y, k1v.z, k1v.w,
                            k2v.x, k2v.y, k2v.z, k2v.w, k3v.x, k3v.y, k3v.z, k3v.w};
#pragma unroll
            for (int j = 0; j < 16; ++j) s[j] += qv * kv[j];
        }

        // mask + row max (across the quad); triple-nest for v_max3
        float msk[16];
#pragma unroll
        for (int j = 0; j < 16; ++j) {
            msk[j] = ms[cg * 16 + j];
            s[j] += msk[j];
        }
        float mx = s[0];
#pragma unroll
        for (int j = 1; j < 15; j += 2) mx = fmaxf(fmaxf(mx, s[j]), s[j + 1]);
        mx = fmaxf(mx, s[15]);
        mx = fmaxf(mx, __shfl_xor(mx, 1));
        mx = fmaxf(mx, __shfl_xor(mx, 2));
        float m_new = fmaxf(m_run, mx);
        float alpha = __expf(m_run - m_new);
        float psum = 0.f;
#pragma unroll
        for (int j = 0; j < 16; ++j) {
            float p = __expf(s[j] - m_new);
            p *= (msk[j] == 0.f) ? 1.f : 0.f;   // robust even if tile fully masked
            s[j] = p;
            psum += p;
        }
        psum += __shfl_xor(psum, 1);
        psum += __shfl_xor(psum, 2);
        l_run = l_run * alpha + psum;
        m_run = m_new;
#pragma unroll
        for (int j = 0; j < 16; ++j) o_acc[j] *= alpha;

        // PV: o[d] += sum_c P[row][c] * v[c][d]  (P broadcast via shfl in quad)
        for (int sc = 0; sc < 4; ++sc) {
#pragma unroll
            for (int jj = 0; jj < 16; ++jj) {
                float pv = __shfl(s[jj], base_lane + sc, 64);
                int c = sc * 16 + jj;
                const float4* vp = (const float4*)&vs[c][cg * 16];
                float4 v0 = vp[0], v1 = vp[1], v2 = vp[2], v3 = vp[3];
                float vv[16] = {v0.x, v0.y, v0.z, v0.w, v1.x, v1.y, v1.z, v1.w,
                                v2.x, v2.y, v2.z, v2.w, v3.x, v3.y, v3.z, v3.w};
#pragma unroll
                for (int j = 0; j < 16; ++j) o_acc[j] += pv * vv[j];
            }
        }
    }

    const float inv_l = 1.f / l_run;
    float* obase = o + ((long)(b * LQ + q0 + row)) * DM + h * DK + cg * 16;
#pragma unroll
    for (int w = 0; w < 4; ++w) {
        float4 r0 = make_float4(o_acc[4 * w + 0] * inv_l, o_acc[4 * w + 1] * inv_l,
                                o_acc[4 * w + 2] * inv_l, o_acc[4 * w + 3] * inv_l);
        *(float4*)(obase + 4 * w) = r0;
    }
}

// ---------------------------------------------------------------------------
// LayerNorm over last dim (512). One wave per row; 8 floats per lane.
// ---------------------------------------------------------------------------
__global__ __launch_bounds__(256) void ln_kernel(const float* __restrict__ x,
                                                 const float* __restrict__ gamma,
                                                 const float* __restrict__ beta,
                                                 float* __restrict__ out)
{
    const int wave = threadIdx.x >> 6;
    const int lane = threadIdx.x & 63;
    const long row = (long)blockIdx.x * 4 + wave;
    const float* xr = x + row * DM + lane * 8;
    float4 a = *(const float4*)xr;
    float4 b = *(const float4*)(xr + 4);
    float sum = a.x + a.y + a.z + a.w + b.x + b.y + b.z + b.w;
    float sq  = a.x * a.x + a.y * a.y + a.z * a.z + a.w * a.w +
                b.x * b.x + b.y * b.y + b.z * b.z + b.w * b.w;
#pragma unroll
    for (int m = 1; m < 64; m <<= 1) {
        sum += __shfl_xor(sum, m);
        sq  += __shfl_xor(sq, m);
    }
    const float mu  = sum * (1.f / 512.f);
    const float var = sq * (1.f / 512.f) - mu * mu;
    const float rs  = 1.0f / sqrtf(var + LN_EPS);

    float4 g0 = *(const float4*)(gamma + lane * 8);
    float4 g1 = *(const float4*)(gamma + lane * 8 + 4);
    float4 t0 = *(const float4*)(beta + lane * 8);
    float4 t1 = *(const float4*)(beta + lane * 8 + 4);
    float4 o0 = make_float4((a.x - mu) * rs * g0.x + t0.x,
                            (a.y - mu) * rs * g0.y + t0.y,
                            (a.z - mu) * rs * g0.z + t0.z,
                            (a.w - mu) * rs * g0.w + t0.w);
    float4 o1 = make_float4((b.x - mu) * rs * g1.x + t1.x,
                            (b.y - mu) * rs * g1.y + t1.y,
                            (b.z - mu) * rs * g1.z + t1.z,
                            (b.w - mu) * rs * g1.w + t1.w);
    *(float4*)(out + row * DM + lane * 8) = o0;
    *(float4*)(out + row * DM + lane * 8 + 4) = o1;
}

// ---------------------------------------------------------------------------
extern "C" void kernel_launch(void* const* d_in, const int* in_sizes, int n_in,
                              void* d_out, int out_size, void* d_ws, size_t ws_size,
                              hipStream_t stream)
{
    const float* Q    = (const float*)d_in[0];
    const float* K    = (const float*)d_in[1];
    const float* V    = (const float*)d_in[2];
    // d_in[3] = node_num (unused; Lk fixed at 2048)
    const int*   mask = (const int*)d_in[4];
    const float* Wq   = (const float*)d_in[5];
    const float* bq   = (const float*)d_in[6];
    const float* Wk   = (const float*)d_in[7];
    const float* bk   = (const float*)d_in[8];
    const float* Wv   = (const float*)d_in[9];
    const float* bv   = (const float*)d_in[10];
    const float* Wo   = (const float*)d_in[11];
    const float* bo   = (const float*)d_in[12];
    const float* gamma= (const float*)d_in[13];
    const float* beta = (const float*)d_in[14];
    float* out = (float*)d_out;

    float* ws  = (float*)d_ws;
    float* qp  = ws;                               // 4096*512
    float* kp  = qp + (long)4096 * 512;            // 8192*512
    float* vp  = kp + (long)8192 * 512;            // 8192*512
    float* ao  = vp + (long)8192 * 512;            // 4096*512
    float* tmp = ao + (long)4096 * 512;            // 4096*512
    // total ws use: 14,680,064 floats = 56 MB

    gemm_bt<<<dim3(4, 64),  256, 0, stream>>>(Q, Wq, bq, nullptr, qp);
    gemm_bt<<<dim3(4, 128), 256, 0, stream>>>(K, Wk, bk, nullptr, kp);
    gemm_bt<<<dim3(4, 128), 256, 0, stream>>>(V, Wv, bv, nullptr, vp);
    attn_kernel<<<dim3(16, 32), 256, 0, stream>>>(qp, kp, vp, mask, ao);
    gemm_bt<<<dim3(4, 64),  256, 0, stream>>>(ao, Wo, bo, Q, tmp);
    ln_kernel<<<1024, 256, 0, stream>>>(tmp, gamma, beta, out);
}

// Round 5
// 669.180 us; speedup vs baseline: 1.0515x; 1.0515x over previous
//
#include <hip/hip_runtime.h>
#include <math.h>

#define H 8
#define DM 512
#define DK 64
#define LQ 1024
#define LK 2048
#define BATCH 4
#define LN_EPS 1e-5f

// ---------------------------------------------------------------------------
// GEMM body: C[m0+64][n0+128] = A[.][512] * W[512][512]^T + bias (+ resid)
// Tile: BM=64 x BN=128, BK=32. 256 threads, each computes 4x8.
// ---------------------------------------------------------------------------
#define BM 64
#define BN 128
#define BK 32

__device__ __forceinline__ void gemm_body(const float* __restrict__ A,
                                          const float* __restrict__ W,
                                          const float* __restrict__ bias,
                                          const float* __restrict__ resid,
                                          float* __restrict__ C,
                                          long m0, int n0)
{
    __shared__ float As[BK][BM + 4];   // [kk][row]
    __shared__ float Bs[BK][BN + 4];   // [kk][col]
    const int tid = threadIdx.x;
    const int tx = tid & 15;          // column groups
    const int ty = tid >> 4;          // row groups

    float acc[4][8];
#pragma unroll
    for (int i = 0; i < 4; ++i)
#pragma unroll
        for (int j = 0; j < 8; ++j) acc[i][j] = 0.f;

    for (int k0 = 0; k0 < DM; k0 += BK) {
#pragma unroll
        for (int t = 0; t < 2; ++t) {
            int i = t * 256 + tid;
            int r = i >> 3, c = (i & 7) * 4;
            float4 v = *(const float4*)(A + (m0 + r) * DM + k0 + c);
            As[c + 0][r] = v.x; As[c + 1][r] = v.y;
            As[c + 2][r] = v.z; As[c + 3][r] = v.w;
        }
#pragma unroll
        for (int t = 0; t < 4; ++t) {
            int i = t * 256 + tid;
            int r = i >> 3, c = (i & 7) * 4;
            float4 v = *(const float4*)(W + (long)(n0 + r) * DM + k0 + c);
            Bs[c + 0][r] = v.x; Bs[c + 1][r] = v.y;
            Bs[c + 2][r] = v.z; Bs[c + 3][r] = v.w;
        }
        __syncthreads();
#pragma unroll 8
        for (int kk = 0; kk < BK; ++kk) {
            float4 a4 = *(const float4*)&As[kk][ty * 4];
            float4 b0 = *(const float4*)&Bs[kk][tx * 4];
            float4 b1 = *(const float4*)&Bs[kk][64 + tx * 4];
            float a[4] = {a4.x, a4.y, a4.z, a4.w};
            float b[8] = {b0.x, b0.y, b0.z, b0.w, b1.x, b1.y, b1.z, b1.w};
#pragma unroll
            for (int i = 0; i < 4; ++i)
#pragma unroll
                for (int j = 0; j < 8; ++j) acc[i][j] += a[i] * b[j];
        }
        __syncthreads();
    }

    float4 blo = *(const float4*)(bias + n0 + tx * 4);
    float4 bhi = *(const float4*)(bias + n0 + 64 + tx * 4);
#pragma unroll
    for (int i = 0; i < 4; ++i) {
        long row = m0 + ty * 4 + i;
        float4 o0 = make_float4(acc[i][0] + blo.x, acc[i][1] + blo.y,
                                acc[i][2] + blo.z, acc[i][3] + blo.w);
        float4 o1 = make_float4(acc[i][4] + bhi.x, acc[i][5] + bhi.y,
                                acc[i][6] + bhi.z, acc[i][7] + bhi.w);
        if (resid) {
            float4 r0 = *(const float4*)(resid + row * DM + n0 + tx * 4);
            float4 r1 = *(const float4*)(resid + row * DM + n0 + 64 + tx * 4);
            o0.x += r0.x; o0.y += r0.y; o0.z += r0.z; o0.w += r0.w;
            o1.x += r1.x; o1.y += r1.y; o1.z += r1.z; o1.w += r1.w;
        }
        *(float4*)(C + row * DM + n0 + tx * 4) = o0;
        *(float4*)(C + row * DM + n0 + 64 + tx * 4) = o1;
    }
}

// Merged Q/K/V projections: flat grid of 1280 blocks (Q:256, K:512, V:512).
__global__ __launch_bounds__(256) void qkv_kernel(const float* __restrict__ Q,
                                                  const float* __restrict__ K,
                                                  const float* __restrict__ V,
                                                  const float* __restrict__ Wq,
                                                  const float* __restrict__ bq,
                                                  const float* __restrict__ Wk,
                                                  const float* __restrict__ bk,
                                                  const float* __restrict__ Wv,
                                                  const float* __restrict__ bv,
                                                  float* __restrict__ qp,
                                                  float* __restrict__ kp,
                                                  float* __restrict__ vp)
{
    const int bx = blockIdx.x;
    const float *A, *W, *bias; float* C; long m0; int n0;
    if (bx < 256) {
        A = Q; W = Wq; bias = bq; C = qp;
        n0 = (bx >> 6) * BN; m0 = (long)(bx & 63) * BM;
    } else if (bx < 768) {
        int t = bx - 256;
        A = K; W = Wk; bias = bk; C = kp;
        n0 = (t >> 7) * BN; m0 = (long)(t & 127) * BM;
    } else {
        int t = bx - 768;
        A = V; W = Wv; bias = bv; C = vp;
        n0 = (t >> 7) * BN; m0 = (long)(t & 127) * BM;
    }
    gemm_body(A, W, bias, nullptr, C, m0, n0);
}

// Output projection (+bias+residual): grid dim3(4, 64).
__global__ __launch_bounds__(256) void ogemm_kernel(const float* __restrict__ A,
                                                    const float* __restrict__ W,
                                                    const float* __restrict__ bias,
                                                    const float* __restrict__ resid,
                                                    float* __restrict__ C)
{
    gemm_body(A, W, bias, resid, C, (long)blockIdx.y * BM, blockIdx.x * BN);
}

// ---------------------------------------------------------------------------
// Flash attention, fp32. One block = one (b,h) x 64 q-rows. 512 threads:
// 8 threads per q-row (octet); thread t: row=t>>3, cg=t&7 owns 8 score
// columns per 64-wide k-tile and d-chunk cg*8..+7 of the output.
// kts staged transposed with XOR-swizzled 16B groups (bank-conflict-free:
// write banks = (m*276+c) mod 32 -> all 32 banks 2-way; reads broadcast).
// 1/sqrt(dk)=0.125 folded into staged q.
// ---------------------------------------------------------------------------
__global__ __launch_bounds__(512, 4) void attn_kernel(const float* __restrict__ q,
                                                      const float* __restrict__ k,
                                                      const float* __restrict__ v,
                                                      const int* __restrict__ mask,
                                                      float* __restrict__ o)
{
    __shared__ __align__(16) float qs[64][68];    // [row][d] (pre-scaled)
    __shared__ __align__(16) float kts[64 * 68];  // [d][c] transposed, swizzled
    __shared__ __align__(16) float vs[64][68];    // [c][d]
    __shared__ float ms[64];

    const int tid = threadIdx.x;
    const int cg  = tid & 7;
    const int row = tid >> 3;
    const int bh  = blockIdx.y;
    const int b   = bh >> 3, h = bh & 7;
    const int q0  = blockIdx.x * 64;

    const float* qbase = q + ((long)(b * LQ + q0)) * DM + h * DK;
    const float* kbase = k + ((long)b * LK) * DM + h * DK;
    const float* vbase = v + ((long)b * LK) * DM + h * DK;

    // stage q tile (64x64), fold in softmax scale
#pragma unroll
    for (int t = 0; t < 2; ++t) {
        int i = t * 512 + tid;
        int r = i >> 4, c = (i & 15) * 4;
        float4 val = *(const float4*)(qbase + (long)r * DM + c);
        val.x *= 0.125f; val.y *= 0.125f; val.z *= 0.125f; val.w *= 0.125f;
        *(float4*)&qs[r][c] = val;
    }

    float m_run = -1e30f, l_run = 0.f;
    float o_acc[8];
#pragma unroll
    for (int j = 0; j < 8; ++j) o_acc[j] = 0.f;

    for (int kt = 0; kt < LK; kt += 64) {
        __syncthreads();   // protect previous tile's LDS
        // stage k (transposed + swizzled) and v
#pragma unroll
        for (int t = 0; t < 2; ++t) {
            int i = t * 512 + tid;
            int c = i >> 4;            // key index 0..63
            int dq = (i & 15) * 4;     // d base
            float4 kv = *(const float4*)(kbase + (long)(kt + c) * DM + dq);
            int sw = dq >> 2;          // (d>>2)&15, same for j=0..3
            int pg = ((c >> 2) ^ sw) * 4 + (c & 3);
            kts[(dq + 0) * 68 + pg] = kv.x;
            kts[(dq + 1) * 68 + pg] = kv.y;
            kts[(dq + 2) * 68 + pg] = kv.z;
            kts[(dq + 3) * 68 + pg] = kv.w;
            float4 vv = *(const float4*)(vbase + (long)(kt + c) * DM + dq);
            *(float4*)&vs[c][dq] = vv;
        }
        if (tid < 64) ms[tid] = mask[b * LK + kt + tid] ? 0.f : -1e30f;
        __syncthreads();

        // S = q . k^T for my 8 columns
        float s[8];
#pragma unroll
        for (int j = 0; j < 8; ++j) s[j] = 0.f;
#pragma unroll 4
        for (int kk = 0; kk < 64; ++kk) {
            float qv = qs[row][kk];
            int sw = kk >> 2;
            float4 k0 = *(const float4*)&kts[kk * 68 + (((cg * 2) ^ sw) * 4)];
            float4 k1 = *(const float4*)&kts[kk * 68 + (((cg * 2 + 1) ^ sw) * 4)];
            s[0] += qv * k0.x; s[1] += qv * k0.y; s[2] += qv * k0.z; s[3] += qv * k0.w;
            s[4] += qv * k1.x; s[5] += qv * k1.y; s[6] += qv * k1.z; s[7] += qv * k1.w;
        }

        // mask + row max (across the octet)
        float msk[8];
#pragma unroll
        for (int j = 0; j < 8; ++j) {
            msk[j] = ms[cg * 8 + j];
            s[j] += msk[j];
        }
        float mx = fmaxf(fmaxf(s[0], s[1]), s[2]);
        mx = fmaxf(fmaxf(mx, s[3]), s[4]);
        mx = fmaxf(fmaxf(mx, s[5]), s[6]);
        mx = fmaxf(mx, s[7]);
        mx = fmaxf(mx, __shfl_xor(mx, 1));
        mx = fmaxf(mx, __shfl_xor(mx, 2));
        mx = fmaxf(mx, __shfl_xor(mx, 4));
        float m_new = fmaxf(m_run, mx);
        float alpha = __expf(m_run - m_new);
        float psum = 0.f;
#pragma unroll
        for (int j = 0; j < 8; ++j) {
            float p = __expf(s[j] - m_new);
            p *= (msk[j] == 0.f) ? 1.f : 0.f;   // exact zero if masked
            s[j] = p;
            psum += p;
        }
        psum += __shfl_xor(psum, 1);
        psum += __shfl_xor(psum, 2);
        psum += __shfl_xor(psum, 4);
        l_run = l_run * alpha + psum;
        m_run = m_new;
#pragma unroll
        for (int j = 0; j < 8; ++j) o_acc[j] *= alpha;

        // PV: o[d] += sum_c P[row][c] * v[c][d]; P broadcast within octet
#pragma unroll
        for (int sc = 0; sc < 8; ++sc) {
#pragma unroll
            for (int jj = 0; jj < 8; ++jj) {
                float pv = __shfl(s[jj], sc, 8);
                int c = sc * 8 + jj;
                float4 v0 = *(const float4*)&vs[c][cg * 8];
                float4 v1 = *(const float4*)&vs[c][cg * 8 + 4];
                o_acc[0] += pv * v0.x; o_acc[1] += pv * v0.y;
                o_acc[2] += pv * v0.z; o_acc[3] += pv * v0.w;
                o_acc[4] += pv * v1.x; o_acc[5] += pv * v1.y;
                o_acc[6] += pv * v1.z; o_acc[7] += pv * v1.w;
            }
        }
    }

    const float inv_l = 1.f / l_run;
    float* obase = o + ((long)(b * LQ + q0 + row)) * DM + h * DK + cg * 8;
    float4 r0 = make_float4(o_acc[0] * inv_l, o_acc[1] * inv_l,
                            o_acc[2] * inv_l, o_acc[3] * inv_l);
    float4 r1 = make_float4(o_acc[4] * inv_l, o_acc[5] * inv_l,
                            o_acc[6] * inv_l, o_acc[7] * inv_l);
    *(float4*)(obase) = r0;
    *(float4*)(obase + 4) = r1;
}

// ---------------------------------------------------------------------------
// LayerNorm over last dim (512). One wave per row; 8 floats per lane.
// ---------------------------------------------------------------------------
__global__ __launch_bounds__(256) void ln_kernel(const float* __restrict__ x,
                                                 const float* __restrict__ gamma,
                                                 const float* __restrict__ beta,
                                                 float* __restrict__ out)
{
    const int wave = threadIdx.x >> 6;
    const int lane = threadIdx.x & 63;
    const long row = (long)blockIdx.x * 4 + wave;
    const float* xr = x + row * DM + lane * 8;
    float4 a = *(const float4*)xr;
    float4 b = *(const float4*)(xr + 4);
    float sum = a.x + a.y + a.z + a.w + b.x + b.y + b.z + b.w;
    float sq  = a.x * a.x + a.y * a.y + a.z * a.z + a.w * a.w +
                b.x * b.x + b.y * b.y + b.z * b.z + b.w * b.w;
#pragma unroll
    for (int m = 1; m < 64; m <<= 1) {
        sum += __shfl_xor(sum, m);
        sq  += __shfl_xor(sq, m);
    }
    const float mu  = sum * (1.f / 512.f);
    const float var = sq * (1.f / 512.f) - mu * mu;
    const float rs  = 1.0f / sqrtf(var + LN_EPS);

    float4 g0 = *(const float4*)(gamma + lane * 8);
    float4 g1 = *(const float4*)(gamma + lane * 8 + 4);
    float4 t0 = *(const float4*)(beta + lane * 8);
    float4 t1 = *(const float4*)(beta + lane * 8 + 4);
    float4 o0 = make_float4((a.x - mu) * rs * g0.x + t0.x,
                            (a.y - mu) * rs * g0.y + t0.y,
                            (a.z - mu) * rs * g0.z + t0.z,
                            (a.w - mu) * rs * g0.w + t0.w);
    float4 o1 = make_float4((b.x - mu) * rs * g1.x + t1.x,
                            (b.y - mu) * rs * g1.y + t1.y,
                            (b.z - mu) * rs * g1.z + t1.z,
                            (b.w - mu) * rs * g1.w + t1.w);
    *(float4*)(out + row * DM + lane * 8) = o0;
    *(float4*)(out + row * DM + lane * 8 + 4) = o1;
}

// ---------------------------------------------------------------------------
extern "C" void kernel_launch(void* const* d_in, const int* in_sizes, int n_in,
                              void* d_out, int out_size, void* d_ws, size_t ws_size,
                              hipStream_t stream)
{
    const float* Q    = (const float*)d_in[0];
    const float* K    = (const float*)d_in[1];
    const float* V    = (const float*)d_in[2];
    // d_in[3] = node_num (unused; Lk fixed at 2048)
    const int*   mask = (const int*)d_in[4];
    const float* Wq   = (const float*)d_in[5];
    const float* bq   = (const float*)d_in[6];
    const float* Wk   = (const float*)d_in[7];
    const float* bk   = (const float*)d_in[8];
    const float* Wv   = (const float*)d_in[9];
    const float* bv   = (const float*)d_in[10];
    const float* Wo   = (const float*)d_in[11];
    const float* bo   = (const float*)d_in[12];
    const float* gamma= (const float*)d_in[13];
    const float* beta = (const float*)d_in[14];
    float* out = (float*)d_out;

    float* ws  = (float*)d_ws;
    float* qp  = ws;                               // 4096*512
    float* kp  = qp + (long)4096 * 512;            // 8192*512
    float* vp  = kp + (long)8192 * 512;            // 8192*512
    float* ao  = vp + (long)8192 * 512;            // 4096*512
    float* tmp = ao + (long)4096 * 512;            // 4096*512

    qkv_kernel<<<1280, 256, 0, stream>>>(Q, K, V, Wq, bq, Wk, bk, Wv, bv, qp, kp, vp);
    attn_kernel<<<dim3(16, 32), 512, 0, stream>>>(qp, kp, vp, mask, ao);
    ogemm_kernel<<<dim3(4, 64), 256, 0, stream>>>(ao, Wo, bo, Q, tmp);
    ln_kernel<<<1024, 256, 0, stream>>>(tmp, gamma, beta, out);
}

// Round 7
// 586.363 us; speedup vs baseline: 1.2000x; 1.1412x over previous
//
#include <hip/hip_runtime.h>
#include <math.h>

#define H 8
#define DM 512
#define DK 64
#define LQ 1024
#define LK 2048
#define BATCH 4
#define LN_EPS 1e-5f

// ---------------------------------------------------------------------------
// GEMM body: C[m0+64][n0+128] = A[.][512] * W[512][512]^T + bias (+ resid)
// Tile: BM=64 x BN=128, BK=32. 256 threads, each computes 4x8.  (unchanged)
// ---------------------------------------------------------------------------
#define BM 64
#define BN 128
#define BK 32

__device__ __forceinline__ void gemm_body(const float* __restrict__ A,
                                          const float* __restrict__ W,
                                          const float* __restrict__ bias,
                                          const float* __restrict__ resid,
                                          float* __restrict__ C,
                                          long m0, int n0)
{
    __shared__ float As[BK][BM + 4];   // [kk][row]
    __shared__ float Bs[BK][BN + 4];   // [kk][col]
    const int tid = threadIdx.x;
    const int tx = tid & 15;          // column groups
    const int ty = tid >> 4;          // row groups

    float acc[4][8];
#pragma unroll
    for (int i = 0; i < 4; ++i)
#pragma unroll
        for (int j = 0; j < 8; ++j) acc[i][j] = 0.f;

    for (int k0 = 0; k0 < DM; k0 += BK) {
#pragma unroll
        for (int t = 0; t < 2; ++t) {
            int i = t * 256 + tid;
            int r = i >> 3, c = (i & 7) * 4;
            float4 v = *(const float4*)(A + (m0 + r) * DM + k0 + c);
            As[c + 0][r] = v.x; As[c + 1][r] = v.y;
            As[c + 2][r] = v.z; As[c + 3][r] = v.w;
        }
#pragma unroll
        for (int t = 0; t < 4; ++t) {
            int i = t * 256 + tid;
            int r = i >> 3, c = (i & 7) * 4;
            float4 v = *(const float4*)(W + (long)(n0 + r) * DM + k0 + c);
            Bs[c + 0][r] = v.x; Bs[c + 1][r] = v.y;
            Bs[c + 2][r] = v.z; Bs[c + 3][r] = v.w;
        }
        __syncthreads();
#pragma unroll 8
        for (int kk = 0; kk < BK; ++kk) {
            float4 a4 = *(const float4*)&As[kk][ty * 4];
            float4 b0 = *(const float4*)&Bs[kk][tx * 4];
            float4 b1 = *(const float4*)&Bs[kk][64 + tx * 4];
            float a[4] = {a4.x, a4.y, a4.z, a4.w};
            float b[8] = {b0.x, b0.y, b0.z, b0.w, b1.x, b1.y, b1.z, b1.w};
#pragma unroll
            for (int i = 0; i < 4; ++i)
#pragma unroll
                for (int j = 0; j < 8; ++j) acc[i][j] += a[i] * b[j];
        }
        __syncthreads();
    }

    float4 blo = *(const float4*)(bias + n0 + tx * 4);
    float4 bhi = *(const float4*)(bias + n0 + 64 + tx * 4);
#pragma unroll
    for (int i = 0; i < 4; ++i) {
        long row = m0 + ty * 4 + i;
        float4 o0 = make_float4(acc[i][0] + blo.x, acc[i][1] + blo.y,
                                acc[i][2] + blo.z, acc[i][3] + blo.w);
        float4 o1 = make_float4(acc[i][4] + bhi.x, acc[i][5] + bhi.y,
                                acc[i][6] + bhi.z, acc[i][7] + bhi.w);
        if (resid) {
            float4 r0 = *(const float4*)(resid + row * DM + n0 + tx * 4);
            float4 r1 = *(const float4*)(resid + row * DM + n0 + 64 + tx * 4);
            o0.x += r0.x; o0.y += r0.y; o0.z += r0.z; o0.w += r0.w;
            o1.x += r1.x; o1.y += r1.y; o1.z += r1.z; o1.w += r1.w;
        }
        *(float4*)(C + row * DM + n0 + tx * 4) = o0;
        *(float4*)(C + row * DM + n0 + 64 + tx * 4) = o1;
    }
}

// Merged Q/K/V projections: flat grid of 1280 blocks (Q:256, K:512, V:512).
__global__ __launch_bounds__(256) void qkv_kernel(const float* __restrict__ Q,
                                                  const float* __restrict__ K,
                                                  const float* __restrict__ V,
                                                  const float* __restrict__ Wq,
                                                  const float* __restrict__ bq,
                                                  const float* __restrict__ Wk,
                                                  const float* __restrict__ bk,
                                                  const float* __restrict__ Wv,
                                                  const float* __restrict__ bv,
                                                  float* __restrict__ qp,
                                                  float* __restrict__ kp,
                                                  float* __restrict__ vp)
{
    const int bx = blockIdx.x;
    const float *A, *W, *bias; float* C; long m0; int n0;
    if (bx < 256) {
        A = Q; W = Wq; bias = bq; C = qp;
        n0 = (bx >> 6) * BN; m0 = (long)(bx & 63) * BM;
    } else if (bx < 768) {
        int t = bx - 256;
        A = K; W = Wk; bias = bk; C = kp;
        n0 = (t >> 7) * BN; m0 = (long)(t & 127) * BM;
    } else {
        int t = bx - 768;
        A = V; W = Wv; bias = bv; C = vp;
        n0 = (t >> 7) * BN; m0 = (long)(t & 127) * BM;
    }
    gemm_body(A, W, bias, nullptr, C, m0, n0);
}

// Output projection (+bias+residual): grid dim3(4, 64).
__global__ __launch_bounds__(256) void ogemm_kernel(const float* __restrict__ A,
                                                    const float* __restrict__ W,
                                                    const float* __restrict__ bias,
                                                    const float* __restrict__ resid,
                                                    float* __restrict__ C)
{
    gemm_body(A, W, bias, resid, C, (long)blockIdx.y * BM, blockIdx.x * BN);
}

// ---------------------------------------------------------------------------
// Flash attention, fp32, 4x4 register-blocked (DS-pipe fix).
// Block = (b,h) x 64 q-rows, 256 threads. Thread (rg=t>>4, cg=t&15) owns
// rows rg*4..+3, score cols cg*4..+3 per 64-tile, and output d-chunk cg*4..+3.
// Every LDS read now feeds 16 FMAs (was 4-8); shfl-based P broadcast replaced
// by Ps[c][r] LDS stage (writes even over bank groups, reads broadcast).
// LDS = 4 x 64x64 f32 = 64 KB exactly -> 2 blocks/CU.
// 1/sqrt(dk)=0.125 folded into staged q; mask loaded directly as int4.
// ---------------------------------------------------------------------------
__global__ __launch_bounds__(256) void attn_kernel(const float* __restrict__ q,
                                                   const float* __restrict__ k,
                                                   const float* __restrict__ v,
                                                   const int* __restrict__ mask,
                                                   float* __restrict__ o)
{
    __shared__ __align__(16) float qs[64 * 64];   // [row][d] (pre-scaled)
    __shared__ __align__(16) float kts[64 * 64];  // [d][c] transposed, swizzled
    __shared__ __align__(16) float vs[64 * 64];   // [c][d]
    __shared__ __align__(16) float Ps[64 * 64];   // [c][r]

    const int tid = threadIdx.x;
    const int rg  = tid >> 4;       // 0..15 -> 4-row group
    const int cg  = tid & 15;       // 0..15 -> 4-col / 4-d group
    const int bh  = blockIdx.y;
    const int b   = bh >> 3, h = bh & 7;
    const int q0  = blockIdx.x * 64;

    const float* qbase = q + ((long)(b * LQ + q0)) * DM + h * DK;
    const float* kbase = k + ((long)b * LK) * DM + h * DK;
    const float* vbase = v + ((long)b * LK) * DM + h * DK;
    const int*   mrow  = mask + b * LK;

    // stage q tile (64x64), fold in softmax scale
#pragma unroll
    for (int t = 0; t < 4; ++t) {
        int i = t * 256 + tid;
        int r = i >> 4, c = (i & 15) * 4;
        float4 val = *(const float4*)(qbase + (long)r * DM + c);
        val.x *= 0.125f; val.y *= 0.125f; val.z *= 0.125f; val.w *= 0.125f;
        *(float4*)&qs[r * 64 + c] = val;
    }

    float m_run[4], l_run[4], o_acc[4][4];
#pragma unroll
    for (int rr = 0; rr < 4; ++rr) {
        m_run[rr] = -1e30f; l_run[rr] = 0.f;
#pragma unroll
        for (int jj = 0; jj < 4; ++jj) o_acc[rr][jj] = 0.f;
    }

    for (int kt = 0; kt < LK; kt += 64) {
        __syncthreads();   // previous tile's PV reads done
        // stage k (transposed + swizzled) and v
#pragma unroll
        for (int t = 0; t < 4; ++t) {
            int i = t * 256 + tid;
            int c = i >> 4;            // key index 0..63
            int dq = (i & 15) * 4;     // d base
            float4 kv = *(const float4*)(kbase + (long)(kt + c) * DM + dq);
            int sw = dq >> 2;
            int pg = ((c >> 2) ^ sw) * 4 + (c & 3);
            kts[(dq + 0) * 64 + pg] = kv.x;
            kts[(dq + 1) * 64 + pg] = kv.y;
            kts[(dq + 2) * 64 + pg] = kv.z;
            kts[(dq + 3) * 64 + pg] = kv.w;
            float4 vv = *(const float4*)(vbase + (long)(kt + c) * DM + dq);
            *(float4*)&vs[c * 64 + dq] = vv;
        }
        __syncthreads();

        // mask for my 4 columns
        int4 mk = *(const int4*)(mrow + kt + cg * 4);
        float msk[4];
        msk[0] = mk.x ? 0.f : -1e30f;
        msk[1] = mk.y ? 0.f : -1e30f;
        msk[2] = mk.z ? 0.f : -1e30f;
        msk[3] = mk.w ? 0.f : -1e30f;

        // S[4r][4c] = q . k^T
        float s[4][4];
#pragma unroll
        for (int rr = 0; rr < 4; ++rr)
#pragma unroll
            for (int jj = 0; jj < 4; ++jj) s[rr][jj] = 0.f;

#pragma unroll 2
        for (int kk4 = 0; kk4 < 16; ++kk4) {
            float qa[4][4], ka[4][4];
#pragma unroll
            for (int rr = 0; rr < 4; ++rr) {
                float4 t4 = *(const float4*)&qs[(rg * 4 + rr) * 64 + kk4 * 4];
                qa[rr][0] = t4.x; qa[rr][1] = t4.y; qa[rr][2] = t4.z; qa[rr][3] = t4.w;
            }
            const int pgk = ((cg ^ kk4) << 2);
#pragma unroll
            for (int ii = 0; ii < 4; ++ii) {
                float4 t4 = *(const float4*)&kts[(kk4 * 4 + ii) * 64 + pgk];
                ka[ii][0] = t4.x; ka[ii][1] = t4.y; ka[ii][2] = t4.z; ka[ii][3] = t4.w;
            }
#pragma unroll
            for (int rr = 0; rr < 4; ++rr)
#pragma unroll
                for (int ii = 0; ii < 4; ++ii)
#pragma unroll
                    for (int jj = 0; jj < 4; ++jj)
                        s[rr][jj] += qa[rr][ii] * ka[ii][jj];
        }

        // online softmax (per-row stats; reduce across the 16 lanes of the
        // row-group: lanes rg*16..+15 within the wave, xor 1,2,4,8 in-group)
        float p[4][4];
#pragma unroll
        for (int rr = 0; rr < 4; ++rr) {
#pragma unroll
            for (int jj = 0; jj < 4; ++jj) s[rr][jj] += msk[jj];
            float mx = fmaxf(fmaxf(s[rr][0], s[rr][1]), fmaxf(s[rr][2], s[rr][3]));
            mx = fmaxf(mx, __shfl_xor(mx, 1));
            mx = fmaxf(mx, __shfl_xor(mx, 2));
            mx = fmaxf(mx, __shfl_xor(mx, 4));
            mx = fmaxf(mx, __shfl_xor(mx, 8));
            float m_new = fmaxf(m_run[rr], mx);
            float al = __expf(m_run[rr] - m_new);
            m_run[rr] = m_new;
            float ps = 0.f;
#pragma unroll
            for (int jj = 0; jj < 4; ++jj) {
                float pp = __expf(s[rr][jj] - m_new);
                pp *= (msk[jj] == 0.f) ? 1.f : 0.f;   // exact 0 if masked
                p[rr][jj] = pp;
                ps += pp;
            }
            ps += __shfl_xor(ps, 1);
            ps += __shfl_xor(ps, 2);
            ps += __shfl_xor(ps, 4);
            ps += __shfl_xor(ps, 8);
            l_run[rr] = l_run[rr] * al + ps;
#pragma unroll
            for (int jj = 0; jj < 4; ++jj) o_acc[rr][jj] *= al;
        }

        // stage P transposed: Ps[c][r]
#pragma unroll
        for (int jj = 0; jj < 4; ++jj) {
            float4 w = make_float4(p[0][jj], p[1][jj], p[2][jj], p[3][jj]);
            *(float4*)&Ps[(cg * 4 + jj) * 64 + rg * 4] = w;
        }
        __syncthreads();

        // PV: o[r][d] += sum_c P[r][c] * V[c][d]
#pragma unroll 4
        for (int cc = 0; cc < 64; ++cc) {
            float4 pv = *(const float4*)&Ps[cc * 64 + rg * 4];
            float4 vv = *(const float4*)&vs[cc * 64 + cg * 4];
            float pa[4] = {pv.x, pv.y, pv.z, pv.w};
            float va[4] = {vv.x, vv.y, vv.z, vv.w};
#pragma unroll
            for (int rr = 0; rr < 4; ++rr)
#pragma unroll
                for (int jj = 0; jj < 4; ++jj)
                    o_acc[rr][jj] += pa[rr] * va[jj];
        }
    }

    // epilogue: normalize and write
#pragma unroll
    for (int rr = 0; rr < 4; ++rr) {
        float inv = 1.f / l_run[rr];
        float4 r0 = make_float4(o_acc[rr][0] * inv, o_acc[rr][1] * inv,
                                o_acc[rr][2] * inv, o_acc[rr][3] * inv);
        *(float4*)(o + ((long)(b * LQ + q0 + rg * 4 + rr)) * DM + h * DK + cg * 4) = r0;
    }
}

// ---------------------------------------------------------------------------
// LayerNorm over last dim (512). One wave per row; 8 floats per lane.
// ---------------------------------------------------------------------------
__global__ __launch_bounds__(256) void ln_kernel(const float* __restrict__ x,
                                                 const float* __restrict__ gamma,
                                                 const float* __restrict__ beta,
                                                 float* __restrict__ out)
{
    const int wave = threadIdx.x >> 6;
    const int lane = threadIdx.x & 63;
    const long row = (long)blockIdx.x * 4 + wave;
    const float* xr = x + row * DM + lane * 8;
    float4 a = *(const float4*)xr;
    float4 b = *(const float4*)(xr + 4);
    float sum = a.x + a.y + a.z + a.w + b.x + b.y + b.z + b.w;
    float sq  = a.x * a.x + a.y * a.y + a.z * a.z + a.w * a.w +
                b.x * b.x + b.y * b.y + b.z * b.z + b.w * b.w;
#pragma unroll
    for (int m = 1; m < 64; m <<= 1) {
        sum += __shfl_xor(sum, m);
        sq  += __shfl_xor(sq, m);
    }
    const float mu  = sum * (1.f / 512.f);
    const float var = sq * (1.f / 512.f) - mu * mu;
    const float rs  = 1.0f / sqrtf(var + LN_EPS);

    float4 g0 = *(const float4*)(gamma + lane * 8);
    float4 g1 = *(const float4*)(gamma + lane * 8 + 4);
    float4 t0 = *(const float4*)(beta + lane * 8);
    float4 t1 = *(const float4*)(beta + lane * 8 + 4);
    float4 o0 = make_float4((a.x - mu) * rs * g0.x + t0.x,
                            (a.y - mu) * rs * g0.y + t0.y,
                            (a.z - mu) * rs * g0.z + t0.z,
                            (a.w - mu) * rs * g0.w + t0.w);
    float4 o1 = make_float4((b.x - mu) * rs * g1.x + t1.x,
                            (b.y - mu) * rs * g1.y + t1.y,
                            (b.z - mu) * rs * g1.z + t1.z,
                            (b.w - mu) * rs * g1.w + t1.w);
    *(float4*)(out + row * DM + lane * 8) = o0;
    *(float4*)(out + row * DM + lane * 8 + 4) = o1;
}

// ---------------------------------------------------------------------------
extern "C" void kernel_launch(void* const* d_in, const int* in_sizes, int n_in,
                              void* d_out, int out_size, void* d_ws, size_t ws_size,
                              hipStream_t stream)
{
    const float* Q    = (const float*)d_in[0];
    const float* K    = (const float*)d_in[1];
    const float* V    = (const float*)d_in[2];
    // d_in[3] = node_num (unused; Lk fixed at 2048)
    const int*   mask = (const int*)d_in[4];
    const float* Wq   = (const float*)d_in[5];
    const float* bq   = (const float*)d_in[6];
    const float* Wk   = (const float*)d_in[7];
    const float* bk   = (const float*)d_in[8];
    const float* Wv   = (const float*)d_in[9];
    const float* bv   = (const float*)d_in[10];
    const float* Wo   = (const float*)d_in[11];
    const float* bo   = (const float*)d_in[12];
    const float* gamma= (const float*)d_in[13];
    const float* beta = (const float*)d_in[14];
    float* out = (float*)d_out;

    float* ws  = (float*)d_ws;
    float* qp  = ws;                               // 4096*512
    float* kp  = qp + (long)4096 * 512;            // 8192*512
    float* vp  = kp + (long)8192 * 512;            // 8192*512
    float* ao  = vp + (long)8192 * 512;            // 4096*512
    float* tmp = ao + (long)4096 * 512;            // 4096*512

    qkv_kernel<<<1280, 256, 0, stream>>>(Q, K, V, Wq, bq, Wk, bk, Wv, bv, qp, kp, vp);
    attn_kernel<<<dim3(16, 32), 256, 0, stream>>>(qp, kp, vp, mask, ao);
    ogemm_kernel<<<dim3(4, 64), 256, 0, stream>>>(ao, Wo, bo, Q, tmp);
    ln_kernel<<<1024, 256, 0, stream>>>(tmp, gamma, beta, out);
}

// Round 10
// 501.120 us; speedup vs baseline: 1.4042x; 1.1701x over previous
//
#include <hip/hip_runtime.h>
#include <math.h>

#define H 8
#define DM 512
#define DK 64
#define LQ 1024
#define LK 2048
#define BATCH 4
#define LN_EPS 1e-5f

typedef short s16x8 __attribute__((ext_vector_type(8)));
typedef float f32x16 __attribute__((ext_vector_type(16)));

// f32 -> bf16 (RNE), returns bits in low 16
__device__ __forceinline__ unsigned int f2bf_rne(unsigned int u) {
    return (u + 0x7fffu + ((u >> 16) & 1u)) >> 16;
}
__device__ __forceinline__ void cvt_split(float x, short& h, short& l) {
    unsigned int u = __float_as_uint(x);
    unsigned int hb = f2bf_rne(u);
    float hf = __uint_as_float(hb << 16);
    unsigned int lb = f2bf_rne(__float_as_uint(x - hf));
    h = (short)hb; l = (short)lb;
}

// ---------------------------------------------------------------------------
// Split-bf16 MFMA GEMM: C[M][512] = A[M][512] * W[512][512]^T + bias (+resid)
// hi/lo decomposition: a*b ~= ah*bh + ah*bl + al*bh  (fp32-grade accuracy).
// Block 128x128, BK=32, 256 thr = 4 waves; wave (wm,wn) owns 64x64 via
// 2x2 fragments of v_mfma_f32_32x32x16_bf16.
// LDS rows padded to 40 ushorts (80B, 16B-aligned; frag reads <=4-way).
// ---------------------------------------------------------------------------
#define LDP 40

__device__ __forceinline__ void gemm_mfma_body(const float* __restrict__ A,
                                               const float* __restrict__ W,
                                               const float* __restrict__ bias,
                                               const float* __restrict__ resid,
                                               float* __restrict__ C,
                                               long m0, int n0)
{
    __shared__ __align__(16) short Ah[128 * LDP];
    __shared__ __align__(16) short Al[128 * LDP];
    __shared__ __align__(16) short Bh[128 * LDP];
    __shared__ __align__(16) short Bl[128 * LDP];

    const int tid = threadIdx.x;
    const int l   = tid & 63;
    const int w   = tid >> 6;
    const int wm  = w >> 1, wn = w & 1;

    f32x16 acc[2][2];
#pragma unroll
    for (int mi = 0; mi < 2; ++mi)
#pragma unroll
        for (int ni = 0; ni < 2; ++ni)
#pragma unroll
            for (int e = 0; e < 16; ++e) acc[mi][ni][e] = 0.f;

    const int srow = tid >> 1;          // 0..127
    const int skb  = (tid & 1) * 16;    // 0 or 16

    for (int k0 = 0; k0 < DM; k0 += 32) {
        __syncthreads();
        // ---- stage A rows (m0+srow), k [k0+skb, +16) ----
        {
            const float* src = A + (m0 + srow) * DM + k0 + skb;
            float fa[16];
            *(float4*)&fa[0]  = *(const float4*)(src + 0);
            *(float4*)&fa[4]  = *(const float4*)(src + 4);
            *(float4*)&fa[8]  = *(const float4*)(src + 8);
            *(float4*)&fa[12] = *(const float4*)(src + 12);
            s16x8 vh0, vl0, vh1, vl1;
#pragma unroll
            for (int j = 0; j < 8; ++j) { short hh, ll; cvt_split(fa[j], hh, ll); vh0[j] = hh; vl0[j] = ll; }
#pragma unroll
            for (int j = 0; j < 8; ++j) { short hh, ll; cvt_split(fa[8 + j], hh, ll); vh1[j] = hh; vl1[j] = ll; }
            *(s16x8*)&Ah[srow * LDP + skb]     = vh0;
            *(s16x8*)&Ah[srow * LDP + skb + 8] = vh1;
            *(s16x8*)&Al[srow * LDP + skb]     = vl0;
            *(s16x8*)&Al[srow * LDP + skb + 8] = vl1;
        }
        // ---- stage W rows (n0+srow), k [k0+skb, +16) ----
        {
            const float* src = W + (long)(n0 + srow) * DM + k0 + skb;
            float fb[16];
            *(float4*)&fb[0]  = *(const float4*)(src + 0);
            *(float4*)&fb[4]  = *(const float4*)(src + 4);
            *(float4*)&fb[8]  = *(const float4*)(src + 8);
            *(float4*)&fb[12] = *(const float4*)(src + 12);
            s16x8 vh0, vl0, vh1, vl1;
#pragma unroll
            for (int j = 0; j < 8; ++j) { short hh, ll; cvt_split(fb[j], hh, ll); vh0[j] = hh; vl0[j] = ll; }
#pragma unroll
            for (int j = 0; j < 8; ++j) { short hh, ll; cvt_split(fb[8 + j], hh, ll); vh1[j] = hh; vl1[j] = ll; }
            *(s16x8*)&Bh[srow * LDP + skb]     = vh0;
            *(s16x8*)&Bh[srow * LDP + skb + 8] = vh1;
            *(s16x8*)&Bl[srow * LDP + skb]     = vl0;
            *(s16x8*)&Bl[srow * LDP + skb + 8] = vl1;
        }
        __syncthreads();

#pragma unroll
        for (int kk = 0; kk < 32; kk += 16) {
            const int ko = kk + (l >> 5) * 8;
            s16x8 ah[2], al[2], bh[2], bl[2];
#pragma unroll
            for (int mi = 0; mi < 2; ++mi) {
                int r = wm * 64 + mi * 32 + (l & 31);
                ah[mi] = *(const s16x8*)&Ah[r * LDP + ko];
                al[mi] = *(const s16x8*)&Al[r * LDP + ko];
            }
#pragma unroll
            for (int ni = 0; ni < 2; ++ni) {
                int r = wn * 64 + ni * 32 + (l & 31);
                bh[ni] = *(const s16x8*)&Bh[r * LDP + ko];
                bl[ni] = *(const s16x8*)&Bl[r * LDP + ko];
            }
#pragma unroll
            for (int mi = 0; mi < 2; ++mi)
#pragma unroll
                for (int ni = 0; ni < 2; ++ni) {
                    acc[mi][ni] = __builtin_amdgcn_mfma_f32_32x32x16_bf16(ah[mi], bh[ni], acc[mi][ni], 0, 0, 0);
                    acc[mi][ni] = __builtin_amdgcn_mfma_f32_32x32x16_bf16(ah[mi], bl[ni], acc[mi][ni], 0, 0, 0);
                    acc[mi][ni] = __builtin_amdgcn_mfma_f32_32x32x16_bf16(al[mi], bh[ni], acc[mi][ni], 0, 0, 0);
                }
        }
    }

    // epilogue: C/D mapping col = lane&31, row = (reg&3) + 8*(reg>>2) + 4*(lane>>5)
#pragma unroll
    for (int mi = 0; mi < 2; ++mi)
#pragma unroll
        for (int ni = 0; ni < 2; ++ni) {
            const int n = n0 + wn * 64 + ni * 32 + (l & 31);
            const float bv = bias[n];
            const long mbase = m0 + wm * 64 + mi * 32 + 4 * (l >> 5);
#pragma unroll
            for (int reg = 0; reg < 16; ++reg) {
                long m = mbase + (reg & 3) + 8 * (reg >> 2);
                float val = acc[mi][ni][reg] + bv;
                if (resid) val += resid[m * DM + n];
                C[m * DM + n] = val;
            }
        }
}

// Merged Q/K/V projections: flat grid of 640 blocks (Q:128, K:256, V:256).
__global__ __launch_bounds__(256) void qkv_kernel(const float* __restrict__ Q,
                                                  const float* __restrict__ K,
                                                  const float* __restrict__ V,
                                                  const float* __restrict__ Wq,
                                                  const float* __restrict__ bq,
                                                  const float* __restrict__ Wk,
                                                  const float* __restrict__ bk,
                                                  const float* __restrict__ Wv,
                                                  const float* __restrict__ bv,
                                                  float* __restrict__ qp,
                                                  float* __restrict__ kp,
                                                  float* __restrict__ vp)
{
    const int bx = blockIdx.x;
    const float *A, *W, *bias; float* C; long m0; int n0;
    if (bx < 128) {
        int t = bx;
        A = Q; W = Wq; bias = bq; C = qp;
        m0 = (long)(t >> 2) * 128; n0 = (t & 3) * 128;
    } else if (bx < 384) {
        int t = bx - 128;
        A = K; W = Wk; bias = bk; C = kp;
        m0 = (long)(t >> 2) * 128; n0 = (t & 3) * 128;
    } else {
        int t = bx - 384;
        A = V; W = Wv; bias = bv; C = vp;
        m0 = (long)(t >> 2) * 128; n0 = (t & 3) * 128;
    }
    gemm_mfma_body(A, W, bias, nullptr, C, m0, n0);
}

// Output projection (+bias+residual): flat grid of 128 blocks.
__global__ __launch_bounds__(256) void ogemm_kernel(const float* __restrict__ A,
                                                    const float* __restrict__ W,
                                                    const float* __restrict__ bias,
                                                    const float* __restrict__ resid,
                                                    float* __restrict__ C)
{
    const int bx = blockIdx.x;
    gemm_mfma_body(A, W, bias, resid, C, (long)(bx >> 2) * 128, (bx & 3) * 128);
}

// ---------------------------------------------------------------------------
// Flash attention, fp32, 4x4 register-blocked. UNCHANGED from round 7.
// ---------------------------------------------------------------------------
__global__ __launch_bounds__(256) void attn_kernel(const float* __restrict__ q,
                                                   const float* __restrict__ k,
                                                   const float* __restrict__ v,
                                                   const int* __restrict__ mask,
                                                   float* __restrict__ o)
{
    __shared__ __align__(16) float qs[64 * 68];   // [row][d] (pre-scaled)
    __shared__ __align__(16) float kts[64 * 64];  // [d][c] transposed, swizzled
    __shared__ __align__(16) float vs[64 * 64];   // [c][d]
    __shared__ __align__(16) float Ps[64 * 68];   // [r][c]

    const int tid = threadIdx.x;
    const int rg  = tid >> 4;       // 0..15 -> 4-row group
    const int cg  = tid & 15;       // 0..15 -> 4-col / 4-d group
    const int bh  = blockIdx.y;
    const int b   = bh >> 3, h = bh & 7;
    const int q0  = blockIdx.x * 64;

    const float* qbase = q + ((long)(b * LQ + q0)) * DM + h * DK;
    const float* kbase = k + ((long)b * LK) * DM + h * DK;
    const float* vbase = v + ((long)b * LK) * DM + h * DK;
    const int*   mrow  = mask + b * LK;

    // stage q tile (64x64), fold in softmax scale
#pragma unroll
    for (int t = 0; t < 4; ++t) {
        int i = t * 256 + tid;
        int r = i >> 4, c = (i & 15) * 4;
        float4 val = *(const float4*)(qbase + (long)r * DM + c);
        val.x *= 0.125f; val.y *= 0.125f; val.z *= 0.125f; val.w *= 0.125f;
        *(float4*)&qs[r * 68 + c] = val;
    }

    float m_run[4], l_run[4], o_acc[4][4];
#pragma unroll
    for (int rr = 0; rr < 4; ++rr) {
        m_run[rr] = -1e30f; l_run[rr] = 0.f;
#pragma unroll
        for (int jj = 0; jj < 4; ++jj) o_acc[rr][jj] = 0.f;
    }

    for (int kt = 0; kt < LK; kt += 64) {
        __syncthreads();   // previous tile's PV reads done
        // stage k (transposed + swizzled) and v
#pragma unroll
        for (int t = 0; t < 4; ++t) {
            int i = t * 256 + tid;
            int c = i >> 4;            // key index 0..63
            int dq = (i & 15) * 4;     // d base
            float4 kv = *(const float4*)(kbase + (long)(kt + c) * DM + dq);
            int sw = dq >> 2;
            int pg = ((c >> 2) ^ sw) * 4 + (c & 3);
            kts[(dq + 0) * 64 + pg] = kv.x;
            kts[(dq + 1) * 64 + pg] = kv.y;
            kts[(dq + 2) * 64 + pg] = kv.z;
            kts[(dq + 3) * 64 + pg] = kv.w;
            float4 vv = *(const float4*)(vbase + (long)(kt + c) * DM + dq);
            *(float4*)&vs[c * 64 + dq] = vv;
        }
        __syncthreads();

        // mask for my 4 columns
        int4 mk = *(const int4*)(mrow + kt + cg * 4);
        float msk[4];
        msk[0] = mk.x ? 0.f : -1e30f;
        msk[1] = mk.y ? 0.f : -1e30f;
        msk[2] = mk.z ? 0.f : -1e30f;
        msk[3] = mk.w ? 0.f : -1e30f;

        // S[4r][4c] = q . k^T
        float s[4][4];
#pragma unroll
        for (int rr = 0; rr < 4; ++rr)
#pragma unroll
            for (int jj = 0; jj < 4; ++jj) s[rr][jj] = 0.f;

#pragma unroll 2
        for (int kk4 = 0; kk4 < 16; ++kk4) {
            float qa[4][4], ka[4][4];
#pragma unroll
            for (int rr = 0; rr < 4; ++rr) {
                float4 t4 = *(const float4*)&qs[(rg * 4 + rr) * 68 + kk4 * 4];
                qa[rr][0] = t4.x; qa[rr][1] = t4.y; qa[rr][2] = t4.z; qa[rr][3] = t4.w;
            }
            const int pgk = ((cg ^ kk4) << 2);
#pragma unroll
            for (int ii = 0; ii < 4; ++ii) {
                float4 t4 = *(const float4*)&kts[(kk4 * 4 + ii) * 64 + pgk];
                ka[ii][0] = t4.x; ka[ii][1] = t4.y; ka[ii][2] = t4.z; ka[ii][3] = t4.w;
            }
#pragma unroll
            for (int rr = 0; rr < 4; ++rr)
#pragma unroll
                for (int ii = 0; ii < 4; ++ii)
#pragma unroll
                    for (int jj = 0; jj < 4; ++jj)
                        s[rr][jj] += qa[rr][ii] * ka[ii][jj];
        }

        // online softmax (per-row stats; reduce across the 16 lanes of the
        // row-group: lanes rg*16..+15 within the wave, xor 1,2,4,8 in-group)
        float p[4][4];
#pragma unroll
        for (int rr = 0; rr < 4; ++rr) {
#pragma unroll
            for (int jj = 0; jj < 4; ++jj) s[rr][jj] += msk[jj];
            float mx = fmaxf(fmaxf(s[rr][0], s[rr][1]), fmaxf(s[rr][2], s[rr][3]));
            mx = fmaxf(mx, __shfl_xor(mx, 1));
            mx = fmaxf(mx, __shfl_xor(mx, 2));
            mx = fmaxf(mx, __shfl_xor(mx, 4));
            mx = fmaxf(mx, __shfl_xor(mx, 8));
            float m_new = fmaxf(m_run[rr], mx);
            float al = __expf(m_run[rr] - m_new);
            m_run[rr] = m_new;
            float ps = 0.f;
#pragma unroll
            for (int jj = 0; jj < 4; ++jj) {
                float pp = __expf(s[rr][jj] - m_new);
                pp *= (msk[jj] == 0.f) ? 1.f : 0.f;   // exact 0 if masked
                p[rr][jj] = pp;
                ps += pp;
            }
            ps += __shfl_xor(ps, 1);
            ps += __shfl_xor(ps, 2);
            ps += __shfl_xor(ps, 4);
            ps += __shfl_xor(ps, 8);
            l_run[rr] = l_run[rr] * al + ps;
#pragma unroll
            for (int jj = 0; jj < 4; ++jj) o_acc[rr][jj] *= al;
        }

        // stage P in [r][c] layout: full 256B row spans per write (bank-even)
#pragma unroll
        for (int rr = 0; rr < 4; ++rr) {
            float4 w = make_float4(p[rr][0], p[rr][1], p[rr][2], p[rr][3]);
            *(float4*)&Ps[(rg * 4 + rr) * 68 + cg * 4] = w;
        }
        __syncthreads();

        // PV: o[r][d] += sum_c P[r][c] * V[c][d]
#pragma unroll 2
        for (int cc4 = 0; cc4 < 16; ++cc4) {
            float pa[4][4], va[4][4];
#pragma unroll
            for (int rr = 0; rr < 4; ++rr) {
                float4 t4 = *(const float4*)&Ps[(rg * 4 + rr) * 68 + cc4 * 4];
                pa[rr][0] = t4.x; pa[rr][1] = t4.y; pa[rr][2] = t4.z; pa[rr][3] = t4.w;
            }
#pragma unroll
            for (int ii = 0; ii < 4; ++ii) {
                float4 t4 = *(const float4*)&vs[(cc4 * 4 + ii) * 64 + cg * 4];
                va[ii][0] = t4.x; va[ii][1] = t4.y; va[ii][2] = t4.z; va[ii][3] = t4.w;
            }
#pragma unroll
            for (int rr = 0; rr < 4; ++rr)
#pragma unroll
                for (int ii = 0; ii < 4; ++ii)
#pragma unroll
                    for (int jj = 0; jj < 4; ++jj)
                        o_acc[rr][jj] += pa[rr][ii] * va[ii][jj];
        }
    }

    // epilogue: normalize and write
#pragma unroll
    for (int rr = 0; rr < 4; ++rr) {
        float inv = 1.f / l_run[rr];
        float4 r0 = make_float4(o_acc[rr][0] * inv, o_acc[rr][1] * inv,
                                o_acc[rr][2] * inv, o_acc[rr][3] * inv);
        *(float4*)(o + ((long)(b * LQ + q0 + rg * 4 + rr)) * DM + h * DK + cg * 4) = r0;
    }
}

// ---------------------------------------------------------------------------
// LayerNorm over last dim (512). One wave per row; 8 floats per lane.
// ---------------------------------------------------------------------------
__global__ __launch_bounds__(256) void ln_kernel(const float* __restrict__ x,
                                                 const float* __restrict__ gamma,
                                                 const float* __restrict__ beta,
                                                 float* __restrict__ out)
{
    const int wave = threadIdx.x >> 6;
    const int lane = threadIdx.x & 63;
    const long row = (long)blockIdx.x * 4 + wave;
    const float* xr = x + row * DM + lane * 8;
    float4 a = *(const float4*)xr;
    float4 b = *(const float4*)(xr + 4);
    float sum = a.x + a.y + a.z + a.w + b.x + b.y + b.z + b.w;
    float sq  = a.x * a.x + a.y * a.y + a.z * a.z + a.w * a.w +
                b.x * b.x + b.y * b.y + b.z * b.z + b.w * b.w;
#pragma unroll
    for (int m = 1; m < 64; m <<= 1) {
        sum += __shfl_xor(sum, m);
        sq  += __shfl_xor(sq, m);
    }
    const float mu  = sum * (1.f / 512.f);
    const float var = sq * (1.f / 512.f) - mu * mu;
    const float rs  = 1.0f / sqrtf(var + LN_EPS);

    float4 g0 = *(const float4*)(gamma + lane * 8);
    float4 g1 = *(const float4*)(gamma + lane * 8 + 4);
    float4 t0 = *(const float4*)(beta + lane * 8);
    float4 t1 = *(const float4*)(beta + lane * 8 + 4);
    float4 o0 = make_float4((a.x - mu) * rs * g0.x + t0.x,
                            (a.y - mu) * rs * g0.y + t0.y,
                            (a.z - mu) * rs * g0.z + t0.z,
                            (a.w - mu) * rs * g0.w + t0.w);
    float4 o1 = make_float4((b.x - mu) * rs * g1.x + t1.x,
                            (b.y - mu) * rs * g1.y + t1.y,
                            (b.z - mu) * rs * g1.z + t1.z,
                            (b.w - mu) * rs * g1.w + t1.w);
    *(float4*)(out + row * DM + lane * 8) = o0;
    *(float4*)(out + row * DM + lane * 8 + 4) = o1;
}

// ---------------------------------------------------------------------------
extern "C" void kernel_launch(void* const* d_in, const int* in_sizes, int n_in,
                              void* d_out, int out_size, void* d_ws, size_t ws_size,
                              hipStream_t stream)
{
    const float* Q    = (const float*)d_in[0];
    const float* K    = (const float*)d_in[1];
    const float* V    = (const float*)d_in[2];
    // d_in[3] = node_num (unused; Lk fixed at 2048)
    const int*   mask = (const int*)d_in[4];
    const float* Wq   = (const float*)d_in[5];
    const float* bq   = (const float*)d_in[6];
    const float* Wk   = (const float*)d_in[7];
    const float* bk   = (const float*)d_in[8];
    const float* Wv   = (const float*)d_in[9];
    const float* bv   = (const float*)d_in[10];
    const float* Wo   = (const float*)d_in[11];
    const float* bo   = (const float*)d_in[12];
    const float* gamma= (const float*)d_in[13];
    const float* beta = (const float*)d_in[14];
    float* out = (float*)d_out;

    float* ws  = (float*)d_ws;
    float* qp  = ws;                               // 4096*512
    float* kp  = qp + (long)4096 * 512;            // 8192*512
    float* vp  = kp + (long)8192 * 512;            // 8192*512
    float* ao  = vp + (long)8192 * 512;            // 4096*512
    float* tmp = ao + (long)4096 * 512;            // 4096*512

    qkv_kernel<<<640, 256, 0, stream>>>(Q, K, V, Wq, bq, Wk, bk, Wv, bv, qp, kp, vp);
    attn_kernel<<<dim3(16, 32), 256, 0, stream>>>(qp, kp, vp, mask, ao);
    ogemm_kernel<<<128, 256, 0, stream>>>(ao, Wo, bo, Q, tmp);
    ln_kernel<<<1024, 256, 0, stream>>>(tmp, gamma, beta, out);
}

// Round 11
// 314.504 us; speedup vs baseline: 2.2373x; 1.5934x over previous
//
#include <hip/hip_runtime.h>
#include <math.h>

#define H 8
#define DM 512
#define DK 64
#define LQ 1024
#define LK 2048
#define BATCH 4
#define LN_EPS 1e-5f

typedef short s16x8 __attribute__((ext_vector_type(8)));
typedef float f32x16 __attribute__((ext_vector_type(16)));

union U32x4 { unsigned u[4]; s16x8 v; };

// f32 -> bf16 (RNE), bits in low 16
__device__ __forceinline__ unsigned f2bf_rne(unsigned u) {
    return (u + 0x7fffu + ((u >> 16) & 1u)) >> 16;
}
__device__ __forceinline__ void cvt_split(float x, short& h, short& l) {
    unsigned u = __float_as_uint(x);
    unsigned hb = f2bf_rne(u);
    float hf = __uint_as_float(hb << 16);
    unsigned lb = f2bf_rne(__float_as_uint(x - hf));
    h = (short)hb; l = (short)lb;
}
__device__ __forceinline__ unsigned pack_bf16(float a, float b) {
    return f2bf_rne(__float_as_uint(a)) | (f2bf_rne(__float_as_uint(b)) << 16);
}

// ---------------------------------------------------------------------------
// Split-bf16 MFMA GEMM body (validated round 10). MODE epilogues:
//  0: f32 C (+optional resid)   1: K -> kbh/kbl [b][h][key][d] bf16
//  2: V -> vth/vtl [b][h][d][key] bf16 (transposed)
// ---------------------------------------------------------------------------
#define LDP 40

template <int MODE>
__device__ __forceinline__ void gemm_mfma_body(const float* __restrict__ A,
                                               const float* __restrict__ W,
                                               const float* __restrict__ bias,
                                               const float* __restrict__ resid,
                                               float* __restrict__ C,
                                               short* __restrict__ dsth,
                                               short* __restrict__ dstl,
                                               long m0, int n0)
{
    __shared__ __align__(16) short Ah[128 * LDP];
    __shared__ __align__(16) short Al[128 * LDP];
    __shared__ __align__(16) short Bh[128 * LDP];
    __shared__ __align__(16) short Bl[128 * LDP];

    const int tid = threadIdx.x;
    const int l   = tid & 63;
    const int w   = tid >> 6;
    const int wm  = w >> 1, wn = w & 1;

    f32x16 acc[2][2];
#pragma unroll
    for (int mi = 0; mi < 2; ++mi)
#pragma unroll
        for (int ni = 0; ni < 2; ++ni)
#pragma unroll
            for (int e = 0; e < 16; ++e) acc[mi][ni][e] = 0.f;

    const int srow = tid >> 1;
    const int skb  = (tid & 1) * 16;

    for (int k0 = 0; k0 < DM; k0 += 32) {
        __syncthreads();
        {
            const float* src = A + (m0 + srow) * DM + k0 + skb;
            float fa[16];
            *(float4*)&fa[0]  = *(const float4*)(src + 0);
            *(float4*)&fa[4]  = *(const float4*)(src + 4);
            *(float4*)&fa[8]  = *(const float4*)(src + 8);
            *(float4*)&fa[12] = *(const float4*)(src + 12);
            s16x8 vh0, vl0, vh1, vl1;
#pragma unroll
            for (int j = 0; j < 8; ++j) { short hh, ll; cvt_split(fa[j], hh, ll); vh0[j] = hh; vl0[j] = ll; }
#pragma unroll
            for (int j = 0; j < 8; ++j) { short hh, ll; cvt_split(fa[8 + j], hh, ll); vh1[j] = hh; vl1[j] = ll; }
            *(s16x8*)&Ah[srow * LDP + skb]     = vh0;
            *(s16x8*)&Ah[srow * LDP + skb + 8] = vh1;
            *(s16x8*)&Al[srow * LDP + skb]     = vl0;
            *(s16x8*)&Al[srow * LDP + skb + 8] = vl1;
        }
        {
            const float* src = W + (long)(n0 + srow) * DM + k0 + skb;
            float fb[16];
            *(float4*)&fb[0]  = *(const float4*)(src + 0);
            *(float4*)&fb[4]  = *(const float4*)(src + 4);
            *(float4*)&fb[8]  = *(const float4*)(src + 8);
            *(float4*)&fb[12] = *(const float4*)(src + 12);
            s16x8 vh0, vl0, vh1, vl1;
#pragma unroll
            for (int j = 0; j < 8; ++j) { short hh, ll; cvt_split(fb[j], hh, ll); vh0[j] = hh; vl0[j] = ll; }
#pragma unroll
            for (int j = 0; j < 8; ++j) { short hh, ll; cvt_split(fb[8 + j], hh, ll); vh1[j] = hh; vl1[j] = ll; }
            *(s16x8*)&Bh[srow * LDP + skb]     = vh0;
            *(s16x8*)&Bh[srow * LDP + skb + 8] = vh1;
            *(s16x8*)&Bl[srow * LDP + skb]     = vl0;
            *(s16x8*)&Bl[srow * LDP + skb + 8] = vl1;
        }
        __syncthreads();

#pragma unroll
        for (int kk = 0; kk < 32; kk += 16) {
            const int ko = kk + (l >> 5) * 8;
            s16x8 ah[2], al2[2], bh[2], bl[2];
#pragma unroll
            for (int mi = 0; mi < 2; ++mi) {
                int r = wm * 64 + mi * 32 + (l & 31);
                ah[mi]  = *(const s16x8*)&Ah[r * LDP + ko];
                al2[mi] = *(const s16x8*)&Al[r * LDP + ko];
            }
#pragma unroll
            for (int ni = 0; ni < 2; ++ni) {
                int r = wn * 64 + ni * 32 + (l & 31);
                bh[ni] = *(const s16x8*)&Bh[r * LDP + ko];
                bl[ni] = *(const s16x8*)&Bl[r * LDP + ko];
            }
#pragma unroll
            for (int mi = 0; mi < 2; ++mi)
#pragma unroll
                for (int ni = 0; ni < 2; ++ni) {
                    acc[mi][ni] = __builtin_amdgcn_mfma_f32_32x32x16_bf16(ah[mi],  bh[ni], acc[mi][ni], 0, 0, 0);
                    acc[mi][ni] = __builtin_amdgcn_mfma_f32_32x32x16_bf16(ah[mi],  bl[ni], acc[mi][ni], 0, 0, 0);
                    acc[mi][ni] = __builtin_amdgcn_mfma_f32_32x32x16_bf16(al2[mi], bh[ni], acc[mi][ni], 0, 0, 0);
                }
        }
    }

#pragma unroll
    for (int mi = 0; mi < 2; ++mi)
#pragma unroll
        for (int ni = 0; ni < 2; ++ni) {
            const int n = n0 + wn * 64 + ni * 32 + (l & 31);
            const float bv = bias[n];
            const long mbase = m0 + wm * 64 + mi * 32 + 4 * (l >> 5);
#pragma unroll
            for (int reg = 0; reg < 16; ++reg) {
                long m = mbase + (reg & 3) + 8 * (reg >> 2);
                float val = acc[mi][ni][reg] + bv;
                if (MODE == 0) {
                    if (resid) val += resid[m * DM + n];
                    C[m * DM + n] = val;
                } else {
                    short hv, lv; cvt_split(val, hv, lv);
                    int b2 = (int)(m >> 11), key = (int)(m & 2047);
                    int h2 = n >> 6, d = n & 63;
                    if (MODE == 1) {
                        long idx = ((long)(b2 * 8 + h2) * 2048 + key) * 64 + d;
                        dsth[idx] = hv; dstl[idx] = lv;
                    } else {
                        long idx = ((long)(b2 * 8 + h2) * 64 + d) * 2048 + key;
                        dsth[idx] = hv; dstl[idx] = lv;
                    }
                }
            }
        }
}

// Merged projections: Q:128 (f32 out), K:256 (bf16 hi/lo), V:256 (bf16^T hi/lo)
__global__ __launch_bounds__(256) void qkv_kernel(const float* __restrict__ Q,
                                                  const float* __restrict__ K,
                                                  const float* __restrict__ V,
                                                  const float* __restrict__ Wq,
                                                  const float* __restrict__ bq,
                                                  const float* __restrict__ Wk,
                                                  const float* __restrict__ bk,
                                                  const float* __restrict__ Wv,
                                                  const float* __restrict__ bv,
                                                  float* __restrict__ qp,
                                                  short* __restrict__ kbh,
                                                  short* __restrict__ kbl,
                                                  short* __restrict__ vth,
                                                  short* __restrict__ vtl)
{
    const int bx = blockIdx.x;
    if (bx < 128) {
        gemm_mfma_body<0>(Q, Wq, bq, nullptr, qp, nullptr, nullptr,
                          (long)(bx >> 2) * 128, (bx & 3) * 128);
    } else if (bx < 384) {
        int t = bx - 128;
        gemm_mfma_body<1>(K, Wk, bk, nullptr, nullptr, kbh, kbl,
                          (long)(t >> 2) * 128, (t & 3) * 128);
    } else {
        int t = bx - 384;
        gemm_mfma_body<2>(V, Wv, bv, nullptr, nullptr, vth, vtl,
                          (long)(t >> 2) * 128, (t & 3) * 128);
    }
}

__global__ __launch_bounds__(256) void ogemm_kernel(const float* __restrict__ A,
                                                    const float* __restrict__ W,
                                                    const float* __restrict__ bias,
                                                    const float* __restrict__ resid,
                                                    float* __restrict__ C)
{
    const int bx = blockIdx.x;
    gemm_mfma_body<0>(A, W, bias, resid, C, nullptr, nullptr,
                      (long)(bx >> 2) * 128, (bx & 3) * 128);
}

// ---------------------------------------------------------------------------
// MFMA flash attention. Block = (b,h) x 64 q-rows, 4 waves, 256 thr.
// Wave w streams its own 32-key tiles (kt = 128t + 32w), independent online
// softmax, NO barriers in main loop. S^T = K.Q^T (3-term split, per-wave);
// P->bf16 in-reg + shfl_xor(32) exchange -> PV = V^T.P^T (V hi/lo).
// Final cross-wave combine via LDS. XCD-bijective block swizzle (512=8x64).
// ---------------------------------------------------------------------------
__global__ __launch_bounds__(256, 2) void attn_kernel(const float* __restrict__ qp,
                                                      const short* __restrict__ kbh,
                                                      const short* __restrict__ kbl,
                                                      const short* __restrict__ vth,
                                                      const short* __restrict__ vtl,
                                                      const int* __restrict__ mask,
                                                      float* __restrict__ o)
{
    __shared__ float Obuf[4][64][68];
    __shared__ float mlbuf[4][4][32];

    const int tid = threadIdx.x;
    const int l   = tid & 63;
    const int w   = tid >> 6;
    const int lq  = l & 31;
    const int hi  = l >> 5;

    const int wg  = (blockIdx.x & 7) * 64 + (blockIdx.x >> 3);  // XCD swizzle
    const int q0  = (wg & 15) * 64;
    const int bh  = wg >> 4;
    const int b   = bh >> 3, h = bh & 7;

    // hoist Q fragments (scale 0.125 folded), hi/lo split
    s16x8 Qh[2][4], Ql[2][4];
#pragma unroll
    for (int nq = 0; nq < 2; ++nq)
#pragma unroll
        for (int ks = 0; ks < 4; ++ks) {
            const float* src = qp + ((long)(b * LQ + q0 + nq * 32 + lq)) * DM + h * DK + ks * 16 + hi * 8;
            float4 f0 = *(const float4*)src;
            float4 f1 = *(const float4*)(src + 4);
            float ff[8] = {f0.x, f0.y, f0.z, f0.w, f1.x, f1.y, f1.z, f1.w};
            U32x4 Hh, Ll;
#pragma unroll
            for (int i = 0; i < 4; ++i) {
                short h0, l0, h1, l1;
                cvt_split(ff[2 * i] * 0.125f, h0, l0);
                cvt_split(ff[2 * i + 1] * 0.125f, h1, l1);
                Hh.u[i] = (unsigned short)h0 | ((unsigned)(unsigned short)h1 << 16);
                Ll.u[i] = (unsigned short)l0 | ((unsigned)(unsigned short)l1 << 16);
            }
            Qh[nq][ks] = Hh.v; Ql[nq][ks] = Ll.v;
        }

    const short* kbase_h = kbh + (long)bh * 2048 * 64;
    const short* kbase_l = kbl + (long)bh * 2048 * 64;
    const short* vbase_h = vth + (long)bh * 64 * 2048;
    const short* vbase_l = vtl + (long)bh * 64 * 2048;
    const int*   mrow    = mask + b * LK;

    float m_run[2] = {-1e30f, -1e30f};
    float l_run[2] = {0.f, 0.f};
    f32x16 Oa[2][2];   // [md][nq]
#pragma unroll
    for (int md = 0; md < 2; ++md)
#pragma unroll
        for (int nq = 0; nq < 2; ++nq)
#pragma unroll
            for (int e = 0; e < 16; ++e) Oa[md][nq][e] = 0.f;

    for (int t = 0; t < 16; ++t) {
        const int kt = t * 128 + w * 32;
        const unsigned long long mb = __ballot(mrow[kt + lq] != 0);
        const unsigned mbits = (unsigned)mb;

        // S^T = K . Q^T
        f32x16 S[2];
#pragma unroll
        for (int nq = 0; nq < 2; ++nq)
#pragma unroll
            for (int e = 0; e < 16; ++e) S[nq][e] = 0.f;
#pragma unroll
        for (int ks = 0; ks < 4; ++ks) {
            s16x8 Kh = *(const s16x8*)(kbase_h + (long)(kt + lq) * 64 + ks * 16 + hi * 8);
            s16x8 Kl = *(const s16x8*)(kbase_l + (long)(kt + lq) * 64 + ks * 16 + hi * 8);
#pragma unroll
            for (int nq = 0; nq < 2; ++nq) {
                S[nq] = __builtin_amdgcn_mfma_f32_32x32x16_bf16(Kh, Qh[nq][ks], S[nq], 0, 0, 0);
                S[nq] = __builtin_amdgcn_mfma_f32_32x32x16_bf16(Kh, Ql[nq][ks], S[nq], 0, 0, 0);
                S[nq] = __builtin_amdgcn_mfma_f32_32x32x16_bf16(Kl, Qh[nq][ks], S[nq], 0, 0, 0);
            }
        }

        // online softmax per nq (keys of this tile live in lanes l and l^32)
        unsigned pk_[2][8], xk[2][8];
#pragma unroll
        for (int nq = 0; nq < 2; ++nq) {
            float sv[16];
#pragma unroll
            for (int r = 0; r < 16; ++r) {
                int key = (r & 3) + 8 * (r >> 2) + 4 * hi;
                sv[r] = ((mbits >> key) & 1u) ? S[nq][r] : -1e30f;
            }
            float mx = sv[0];
#pragma unroll
            for (int r = 1; r < 16; ++r) mx = fmaxf(mx, sv[r]);
            mx = fmaxf(mx, __shfl_xor(mx, 32));
            float m_new = fmaxf(m_run[nq], mx);
            float al = __expf(m_run[nq] - m_new);
            m_run[nq] = m_new;
            float pv[16], ps = 0.f;
#pragma unroll
            for (int r = 0; r < 16; ++r) {
                int key = (r & 3) + 8 * (r >> 2) + 4 * hi;
                float p = ((mbits >> key) & 1u) ? __expf(sv[r] - m_new) : 0.f;
                pv[r] = p; ps += p;
            }
            ps += __shfl_xor(ps, 32);
            l_run[nq] = l_run[nq] * al + ps;
#pragma unroll
            for (int md = 0; md < 2; ++md)
#pragma unroll
                for (int e = 0; e < 16; ++e) Oa[md][nq][e] *= al;
#pragma unroll
            for (int i = 0; i < 8; ++i) pk_[nq][i] = pack_bf16(pv[2 * i], pv[2 * i + 1]);
#pragma unroll
            for (int i = 0; i < 8; ++i) xk[nq][i] = (unsigned)__shfl_xor((int)pk_[nq][i], 32);
        }

        // PV: O^T += V^T . P^T  (V split hi/lo)
#pragma unroll
        for (int ks = 0; ks < 2; ++ks) {
            s16x8 Pf[2];
#pragma unroll
            for (int nq = 0; nq < 2; ++nq) {
                U32x4 u;
                if (hi == 0) {
                    u.u[0] = pk_[nq][4 * ks];     u.u[1] = pk_[nq][4 * ks + 1];
                    u.u[2] = xk[nq][4 * ks];      u.u[3] = xk[nq][4 * ks + 1];
                } else {
                    u.u[0] = xk[nq][4 * ks + 2];  u.u[1] = xk[nq][4 * ks + 3];
                    u.u[2] = pk_[nq][4 * ks + 2]; u.u[3] = pk_[nq][4 * ks + 3];
                }
                Pf[nq] = u.v;
            }
#pragma unroll
            for (int md = 0; md < 2; ++md) {
                s16x8 Vh = *(const s16x8*)(vbase_h + (long)(32 * md + lq) * 2048 + kt + ks * 16 + hi * 8);
                s16x8 Vl = *(const s16x8*)(vbase_l + (long)(32 * md + lq) * 2048 + kt + ks * 16 + hi * 8);
#pragma unroll
                for (int nq = 0; nq < 2; ++nq) {
                    Oa[md][nq] = __builtin_amdgcn_mfma_f32_32x32x16_bf16(Vh, Pf[nq], Oa[md][nq], 0, 0, 0);
                    Oa[md][nq] = __builtin_amdgcn_mfma_f32_32x32x16_bf16(Vl, Pf[nq], Oa[md][nq], 0, 0, 0);
                }
            }
        }
    }

    // stash per-wave partials
#pragma unroll
    for (int md = 0; md < 2; ++md)
#pragma unroll
        for (int nq = 0; nq < 2; ++nq)
#pragma unroll
            for (int r = 0; r < 16; ++r) {
                int d = 32 * md + (r & 3) + 8 * (r >> 2) + 4 * hi;
                Obuf[w][d][nq * 32 + lq] = Oa[md][nq][r];
            }
    if (l < 32) {
        mlbuf[w][0][lq] = m_run[0];
        mlbuf[w][1][lq] = m_run[1];
        mlbuf[w][2][lq] = l_run[0];
        mlbuf[w][3][lq] = l_run[1];
    }
    __syncthreads();

    // combine across waves: thread -> (q = tid&63, d-chunk = tid>>6)
    {
        const int q  = tid & 63;
        const int dc = tid >> 6;
        const int qh = q >> 5, qlo = q & 31;
        float mw[4], lw[4];
#pragma unroll
        for (int w2 = 0; w2 < 4; ++w2) {
            mw[w2] = mlbuf[w2][qh][qlo];
            lw[w2] = mlbuf[w2][2 + qh][qlo];
        }
        float ms = fmaxf(fmaxf(mw[0], mw[1]), fmaxf(mw[2], mw[3]));
        float fw[4], Ls = 0.f;
#pragma unroll
        for (int w2 = 0; w2 < 4; ++w2) { fw[w2] = __expf(mw[w2] - ms); Ls += lw[w2] * fw[w2]; }
        float inv = 1.f / Ls;
        float ov[16];
#pragma unroll
        for (int dd = 0; dd < 16; ++dd) {
            int d = dc * 16 + dd;
            float a = Obuf[0][d][q] * fw[0] + Obuf[1][d][q] * fw[1] +
                      Obuf[2][d][q] * fw[2] + Obuf[3][d][q] * fw[3];
            ov[dd] = a * inv;
        }
        float* dst = o + ((long)(b * LQ + q0 + q)) * DM + h * DK + dc * 16;
        *(float4*)(dst + 0)  = *(float4*)&ov[0];
        *(float4*)(dst + 4)  = *(float4*)&ov[4];
        *(float4*)(dst + 8)  = *(float4*)&ov[8];
        *(float4*)(dst + 12) = *(float4*)&ov[12];
    }
}

// ---------------------------------------------------------------------------
// LayerNorm over last dim (512). One wave per row; 8 floats per lane.
// ---------------------------------------------------------------------------
__global__ __launch_bounds__(256) void ln_kernel(const float* __restrict__ x,
                                                 const float* __restrict__ gamma,
                                                 const float* __restrict__ beta,
                                                 float* __restrict__ out)
{
    const int wave = threadIdx.x >> 6;
    const int lane = threadIdx.x & 63;
    const long row = (long)blockIdx.x * 4 + wave;
    const float* xr = x + row * DM + lane * 8;
    float4 a = *(const float4*)xr;
    float4 b = *(const float4*)(xr + 4);
    float sum = a.x + a.y + a.z + a.w + b.x + b.y + b.z + b.w;
    float sq  = a.x * a.x + a.y * a.y + a.z * a.z + a.w * a.w +
                b.x * b.x + b.y * b.y + b.z * b.z + b.w * b.w;
#pragma unroll
    for (int m = 1; m < 64; m <<= 1) {
        sum += __shfl_xor(sum, m);
        sq  += __shfl_xor(sq, m);
    }
    const float mu  = sum * (1.f / 512.f);
    const float var = sq * (1.f / 512.f) - mu * mu;
    const float rs  = 1.0f / sqrtf(var + LN_EPS);

    float4 g0 = *(const float4*)(gamma + lane * 8);
    float4 g1 = *(const float4*)(gamma + lane * 8 + 4);
    float4 t0 = *(const float4*)(beta + lane * 8);
    float4 t1 = *(const float4*)(beta + lane * 8 + 4);
    float4 o0 = make_float4((a.x - mu) * rs * g0.x + t0.x,
                            (a.y - mu) * rs * g0.y + t0.y,
                            (a.z - mu) * rs * g0.z + t0.z,
                            (a.w - mu) * rs * g0.w + t0.w);
    float4 o1 = make_float4((b.x - mu) * rs * g1.x + t1.x,
                            (b.y - mu) * rs * g1.y + t1.y,
                            (b.z - mu) * rs * g1.z + t1.z,
                            (b.w - mu) * rs * g1.w + t1.w);
    *(float4*)(out + row * DM + lane * 8) = o0;
    *(float4*)(out + row * DM + lane * 8 + 4) = o1;
}

// ---------------------------------------------------------------------------
extern "C" void kernel_launch(void* const* d_in, const int* in_sizes, int n_in,
                              void* d_out, int out_size, void* d_ws, size_t ws_size,
                              hipStream_t stream)
{
    const float* Q    = (const float*)d_in[0];
    const float* K    = (const float*)d_in[1];
    const float* V    = (const float*)d_in[2];
    // d_in[3] = node_num (unused; Lk fixed at 2048)
    const int*   mask = (const int*)d_in[4];
    const float* Wq   = (const float*)d_in[5];
    const float* bq   = (const float*)d_in[6];
    const float* Wk   = (const float*)d_in[7];
    const float* bk   = (const float*)d_in[8];
    const float* Wv   = (const float*)d_in[9];
    const float* bv   = (const float*)d_in[10];
    const float* Wo   = (const float*)d_in[11];
    const float* bo   = (const float*)d_in[12];
    const float* gamma= (const float*)d_in[13];
    const float* beta = (const float*)d_in[14];
    float* out = (float*)d_out;

    char* base = (char*)d_ws;
    float* qp  = (float*)(base);                       // 8 MB  (4096x512 f32)
    short* kbh = (short*)(base + (size_t)8  * 1024 * 1024);  // 8 MB
    short* kbl = (short*)(base + (size_t)16 * 1024 * 1024);  // 8 MB
    short* vth = (short*)(base + (size_t)24 * 1024 * 1024);  // 8 MB
    short* vtl = (short*)(base + (size_t)32 * 1024 * 1024);  // 8 MB
    float* ao  = (float*)(base + (size_t)40 * 1024 * 1024);  // 8 MB
    float* tmp = (float*)(base + (size_t)48 * 1024 * 1024);  // 8 MB

    qkv_kernel<<<640, 256, 0, stream>>>(Q, K, V, Wq, bq, Wk, bk, Wv, bv,
                                        qp, kbh, kbl, vth, vtl);
    attn_kernel<<<512, 256, 0, stream>>>(qp, kbh, kbl, vth, vtl, mask, ao);
    ogemm_kernel<<<128, 256, 0, stream>>>(ao, Wo, bo, Q, tmp);
    ln_kernel<<<1024, 256, 0, stream>>>(tmp, gamma, beta, out);
}

// Round 12
// 296.663 us; speedup vs baseline: 2.3719x; 1.0601x over previous
//
#include <hip/hip_runtime.h>
#include <math.h>

#define H 8
#define DM 512
#define DK 64
#define LQ 1024
#define LK 2048
#define BATCH 4
#define LN_EPS 1e-5f

typedef short s16x8 __attribute__((ext_vector_type(8)));
typedef float f32x16 __attribute__((ext_vector_type(16)));

union U32x4 { unsigned u[4]; s16x8 v; };

// f32 -> bf16 (RNE), bits in low 16
__device__ __forceinline__ unsigned f2bf_rne(unsigned u) {
    return (u + 0x7fffu + ((u >> 16) & 1u)) >> 16;
}
__device__ __forceinline__ void cvt_split(float x, short& h, short& l) {
    unsigned u = __float_as_uint(x);
    unsigned hb = f2bf_rne(u);
    float hf = __uint_as_float(hb << 16);
    unsigned lb = f2bf_rne(__float_as_uint(x - hf));
    h = (short)hb; l = (short)lb;
}
__device__ __forceinline__ unsigned pack_bf16(float a, float b) {
    return f2bf_rne(__float_as_uint(a)) | (f2bf_rne(__float_as_uint(b)) << 16);
}

// ---------------------------------------------------------------------------
// Split-bf16 MFMA GEMM body (validated round 10). LDS now passed in by the
// caller (one 40KB set per kernel -- template instantiations previously
// allocated 3x = 120KB, capping occupancy at 1 block/CU).
// MODE: 0 f32 C (+resid); 1 K->bf16 hi/lo [b][h][key][d]; 2 V^T hi/lo.
// ---------------------------------------------------------------------------
#define LDP 40

template <int MODE>
__device__ __forceinline__ void gemm_mfma_body(short* __restrict__ Ah,
                                               short* __restrict__ Al,
                                               short* __restrict__ Bh,
                                               short* __restrict__ Bl,
                                               const float* __restrict__ A,
                                               const float* __restrict__ W,
                                               const float* __restrict__ bias,
                                               const float* __restrict__ resid,
                                               float* __restrict__ C,
                                               short* __restrict__ dsth,
                                               short* __restrict__ dstl,
                                               long m0, int n0)
{
    const int tid = threadIdx.x;
    const int l   = tid & 63;
    const int w   = tid >> 6;
    const int wm  = w >> 1, wn = w & 1;

    f32x16 acc[2][2];
#pragma unroll
    for (int mi = 0; mi < 2; ++mi)
#pragma unroll
        for (int ni = 0; ni < 2; ++ni)
#pragma unroll
            for (int e = 0; e < 16; ++e) acc[mi][ni][e] = 0.f;

    const int srow = tid >> 1;
    const int skb  = (tid & 1) * 16;

    for (int k0 = 0; k0 < DM; k0 += 32) {
        __syncthreads();
        {
            const float* src = A + (m0 + srow) * DM + k0 + skb;
            float fa[16];
            *(float4*)&fa[0]  = *(const float4*)(src + 0);
            *(float4*)&fa[4]  = *(const float4*)(src + 4);
            *(float4*)&fa[8]  = *(const float4*)(src + 8);
            *(float4*)&fa[12] = *(const float4*)(src + 12);
            s16x8 vh0, vl0, vh1, vl1;
#pragma unroll
            for (int j = 0; j < 8; ++j) { short hh, ll; cvt_split(fa[j], hh, ll); vh0[j] = hh; vl0[j] = ll; }
#pragma unroll
            for (int j = 0; j < 8; ++j) { short hh, ll; cvt_split(fa[8 + j], hh, ll); vh1[j] = hh; vl1[j] = ll; }
            *(s16x8*)&Ah[srow * LDP + skb]     = vh0;
            *(s16x8*)&Ah[srow * LDP + skb + 8] = vh1;
            *(s16x8*)&Al[srow * LDP + skb]     = vl0;
            *(s16x8*)&Al[srow * LDP + skb + 8] = vl1;
        }
        {
            const float* src = W + (long)(n0 + srow) * DM + k0 + skb;
            float fb[16];
            *(float4*)&fb[0]  = *(const float4*)(src + 0);
            *(float4*)&fb[4]  = *(const float4*)(src + 4);
            *(float4*)&fb[8]  = *(const float4*)(src + 8);
            *(float4*)&fb[12] = *(const float4*)(src + 12);
            s16x8 vh0, vl0, vh1, vl1;
#pragma unroll
            for (int j = 0; j < 8; ++j) { short hh, ll; cvt_split(fb[j], hh, ll); vh0[j] = hh; vl0[j] = ll; }
#pragma unroll
            for (int j = 0; j < 8; ++j) { short hh, ll; cvt_split(fb[8 + j], hh, ll); vh1[j] = hh; vl1[j] = ll; }
            *(s16x8*)&Bh[srow * LDP + skb]     = vh0;
            *(s16x8*)&Bh[srow * LDP + skb + 8] = vh1;
            *(s16x8*)&Bl[srow * LDP + skb]     = vl0;
            *(s16x8*)&Bl[srow * LDP + skb + 8] = vl1;
        }
        __syncthreads();

#pragma unroll
        for (int kk = 0; kk < 32; kk += 16) {
            const int ko = kk + (l >> 5) * 8;
            s16x8 ah[2], al2[2], bh[2], bl[2];
#pragma unroll
            for (int mi = 0; mi < 2; ++mi) {
                int r = wm * 64 + mi * 32 + (l & 31);
                ah[mi]  = *(const s16x8*)&Ah[r * LDP + ko];
                al2[mi] = *(const s16x8*)&Al[r * LDP + ko];
            }
#pragma unroll
            for (int ni = 0; ni < 2; ++ni) {
                int r = wn * 64 + ni * 32 + (l & 31);
                bh[ni] = *(const s16x8*)&Bh[r * LDP + ko];
                bl[ni] = *(const s16x8*)&Bl[r * LDP + ko];
            }
#pragma unroll
            for (int mi = 0; mi < 2; ++mi)
#pragma unroll
                for (int ni = 0; ni < 2; ++ni) {
                    acc[mi][ni] = __builtin_amdgcn_mfma_f32_32x32x16_bf16(ah[mi],  bh[ni], acc[mi][ni], 0, 0, 0);
                    acc[mi][ni] = __builtin_amdgcn_mfma_f32_32x32x16_bf16(ah[mi],  bl[ni], acc[mi][ni], 0, 0, 0);
                    acc[mi][ni] = __builtin_amdgcn_mfma_f32_32x32x16_bf16(al2[mi], bh[ni], acc[mi][ni], 0, 0, 0);
                }
        }
    }

#pragma unroll
    for (int mi = 0; mi < 2; ++mi)
#pragma unroll
        for (int ni = 0; ni < 2; ++ni) {
            const int n = n0 + wn * 64 + ni * 32 + (l & 31);
            const float bv = bias[n];
            const long mbase = m0 + wm * 64 + mi * 32 + 4 * (l >> 5);
#pragma unroll
            for (int reg = 0; reg < 16; ++reg) {
                long m = mbase + (reg & 3) + 8 * (reg >> 2);
                float val = acc[mi][ni][reg] + bv;
                if (MODE == 0) {
                    if (resid) val += resid[m * DM + n];
                    C[m * DM + n] = val;
                } else {
                    short hv, lv; cvt_split(val, hv, lv);
                    int b2 = (int)(m >> 11), key = (int)(m & 2047);
                    int h2 = n >> 6, d = n & 63;
                    if (MODE == 1) {
                        long idx = ((long)(b2 * 8 + h2) * 2048 + key) * 64 + d;
                        dsth[idx] = hv; dstl[idx] = lv;
                    } else {
                        long idx = ((long)(b2 * 8 + h2) * 64 + d) * 2048 + key;
                        dsth[idx] = hv; dstl[idx] = lv;
                    }
                }
            }
        }
}

// Merged projections: Q:128 (f32 out), K:256 (bf16 hi/lo), V:256 (bf16^T hi/lo)
__global__ __launch_bounds__(256, 4) void qkv_kernel(const float* __restrict__ Q,
                                                     const float* __restrict__ K,
                                                     const float* __restrict__ V,
                                                     const float* __restrict__ Wq,
                                                     const float* __restrict__ bq,
                                                     const float* __restrict__ Wk,
                                                     const float* __restrict__ bk,
                                                     const float* __restrict__ Wv,
                                                     const float* __restrict__ bv,
                                                     float* __restrict__ qp,
                                                     short* __restrict__ kbh,
                                                     short* __restrict__ kbl,
                                                     short* __restrict__ vth,
                                                     short* __restrict__ vtl)
{
    __shared__ __align__(16) short Ah[128 * LDP];
    __shared__ __align__(16) short Al[128 * LDP];
    __shared__ __align__(16) short Bh[128 * LDP];
    __shared__ __align__(16) short Bl[128 * LDP];

    const int bx = blockIdx.x;
    if (bx < 128) {
        gemm_mfma_body<0>(Ah, Al, Bh, Bl, Q, Wq, bq, nullptr, qp, nullptr, nullptr,
                          (long)(bx >> 2) * 128, (bx & 3) * 128);
    } else if (bx < 384) {
        int t = bx - 128;
        gemm_mfma_body<1>(Ah, Al, Bh, Bl, K, Wk, bk, nullptr, nullptr, kbh, kbl,
                          (long)(t >> 2) * 128, (t & 3) * 128);
    } else {
        int t = bx - 384;
        gemm_mfma_body<2>(Ah, Al, Bh, Bl, V, Wv, bv, nullptr, nullptr, vth, vtl,
                          (long)(t >> 2) * 128, (t & 3) * 128);
    }
}

__global__ __launch_bounds__(256, 4) void ogemm_kernel(const float* __restrict__ A,
                                                       const float* __restrict__ W,
                                                       const float* __restrict__ bias,
                                                       const float* __restrict__ resid,
                                                       float* __restrict__ C)
{
    __shared__ __align__(16) short Ah[128 * LDP];
    __shared__ __align__(16) short Al[128 * LDP];
    __shared__ __align__(16) short Bh[128 * LDP];
    __shared__ __align__(16) short Bl[128 * LDP];

    const int bx = blockIdx.x;
    gemm_mfma_body<0>(Ah, Al, Bh, Bl, A, W, bias, resid, C, nullptr, nullptr,
                      (long)(bx >> 2) * 128, (bx & 3) * 128);
}

// ---------------------------------------------------------------------------
// MFMA flash attention (UNCHANGED from round 11 -- validated, <105 us).
// ---------------------------------------------------------------------------
__global__ __launch_bounds__(256, 2) void attn_kernel(const float* __restrict__ qp,
                                                      const short* __restrict__ kbh,
                                                      const short* __restrict__ kbl,
                                                      const short* __restrict__ vth,
                                                      const short* __restrict__ vtl,
                                                      const int* __restrict__ mask,
                                                      float* __restrict__ o)
{
    __shared__ float Obuf[4][64][68];
    __shared__ float mlbuf[4][4][32];

    const int tid = threadIdx.x;
    const int l   = tid & 63;
    const int w   = tid >> 6;
    const int lq  = l & 31;
    const int hi  = l >> 5;

    const int wg  = (blockIdx.x & 7) * 64 + (blockIdx.x >> 3);  // XCD swizzle
    const int q0  = (wg & 15) * 64;
    const int bh  = wg >> 4;
    const int b   = bh >> 3, h = bh & 7;

    // hoist Q fragments (scale 0.125 folded), hi/lo split
    s16x8 Qh[2][4], Ql[2][4];
#pragma unroll
    for (int nq = 0; nq < 2; ++nq)
#pragma unroll
        for (int ks = 0; ks < 4; ++ks) {
            const float* src = qp + ((long)(b * LQ + q0 + nq * 32 + lq)) * DM + h * DK + ks * 16 + hi * 8;
            float4 f0 = *(const float4*)src;
            float4 f1 = *(const float4*)(src + 4);
            float ff[8] = {f0.x, f0.y, f0.z, f0.w, f1.x, f1.y, f1.z, f1.w};
            U32x4 Hh, Ll;
#pragma unroll
            for (int i = 0; i < 4; ++i) {
                short h0, l0, h1, l1;
                cvt_split(ff[2 * i] * 0.125f, h0, l0);
                cvt_split(ff[2 * i + 1] * 0.125f, h1, l1);
                Hh.u[i] = (unsigned short)h0 | ((unsigned)(unsigned short)h1 << 16);
                Ll.u[i] = (unsigned short)l0 | ((unsigned)(unsigned short)l1 << 16);
            }
            Qh[nq][ks] = Hh.v; Ql[nq][ks] = Ll.v;
        }

    const short* kbase_h = kbh + (long)bh * 2048 * 64;
    const short* kbase_l = kbl + (long)bh * 2048 * 64;
    const short* vbase_h = vth + (long)bh * 64 * 2048;
    const short* vbase_l = vtl + (long)bh * 64 * 2048;
    const int*   mrow    = mask + b * LK;

    float m_run[2] = {-1e30f, -1e30f};
    float l_run[2] = {0.f, 0.f};
    f32x16 Oa[2][2];   // [md][nq]
#pragma unroll
    for (int md = 0; md < 2; ++md)
#pragma unroll
        for (int nq = 0; nq < 2; ++nq)
#pragma unroll
            for (int e = 0; e < 16; ++e) Oa[md][nq][e] = 0.f;

    for (int t = 0; t < 16; ++t) {
        const int kt = t * 128 + w * 32;
        const unsigned long long mb = __ballot(mrow[kt + lq] != 0);
        const unsigned mbits = (unsigned)mb;

        // S^T = K . Q^T
        f32x16 S[2];
#pragma unroll
        for (int nq = 0; nq < 2; ++nq)
#pragma unroll
            for (int e = 0; e < 16; ++e) S[nq][e] = 0.f;
#pragma unroll
        for (int ks = 0; ks < 4; ++ks) {
            s16x8 Kh = *(const s16x8*)(kbase_h + (long)(kt + lq) * 64 + ks * 16 + hi * 8);
            s16x8 Kl = *(const s16x8*)(kbase_l + (long)(kt + lq) * 64 + ks * 16 + hi * 8);
#pragma unroll
            for (int nq = 0; nq < 2; ++nq) {
                S[nq] = __builtin_amdgcn_mfma_f32_32x32x16_bf16(Kh, Qh[nq][ks], S[nq], 0, 0, 0);
                S[nq] = __builtin_amdgcn_mfma_f32_32x32x16_bf16(Kh, Ql[nq][ks], S[nq], 0, 0, 0);
                S[nq] = __builtin_amdgcn_mfma_f32_32x32x16_bf16(Kl, Qh[nq][ks], S[nq], 0, 0, 0);
            }
        }

        // online softmax per nq (keys of this tile live in lanes l and l^32)
        unsigned pk_[2][8], xk[2][8];
#pragma unroll
        for (int nq = 0; nq < 2; ++nq) {
            float sv[16];
#pragma unroll
            for (int r = 0; r < 16; ++r) {
                int key = (r & 3) + 8 * (r >> 2) + 4 * hi;
                sv[r] = ((mbits >> key) & 1u) ? S[nq][r] : -1e30f;
            }
            float mx = sv[0];
#pragma unroll
            for (int r = 1; r < 16; ++r) mx = fmaxf(mx, sv[r]);
            mx = fmaxf(mx, __shfl_xor(mx, 32));
            float m_new = fmaxf(m_run[nq], mx);
            float al = __expf(m_run[nq] - m_new);
            m_run[nq] = m_new;
            float pv[16], ps = 0.f;
#pragma unroll
            for (int r = 0; r < 16; ++r) {
                int key = (r & 3) + 8 * (r >> 2) + 4 * hi;
                float p = ((mbits >> key) & 1u) ? __expf(sv[r] - m_new) : 0.f;
                pv[r] = p; ps += p;
            }
            ps += __shfl_xor(ps, 32);
            l_run[nq] = l_run[nq] * al + ps;
#pragma unroll
            for (int md = 0; md < 2; ++md)
#pragma unroll
                for (int e = 0; e < 16; ++e) Oa[md][nq][e] *= al;
#pragma unroll
            for (int i = 0; i < 8; ++i) pk_[nq][i] = pack_bf16(pv[2 * i], pv[2 * i + 1]);
#pragma unroll
            for (int i = 0; i < 8; ++i) xk[nq][i] = (unsigned)__shfl_xor((int)pk_[nq][i], 32);
        }

        // PV: O^T += V^T . P^T  (V split hi/lo)
#pragma unroll
        for (int ks = 0; ks < 2; ++ks) {
            s16x8 Pf[2];
#pragma unroll
            for (int nq = 0; nq < 2; ++nq) {
                U32x4 u;
                if (hi == 0) {
                    u.u[0] = pk_[nq][4 * ks];     u.u[1] = pk_[nq][4 * ks + 1];
                    u.u[2] = xk[nq][4 * ks];      u.u[3] = xk[nq][4 * ks + 1];
                } else {
                    u.u[0] = xk[nq][4 * ks + 2];  u.u[1] = xk[nq][4 * ks + 3];
                    u.u[2] = pk_[nq][4 * ks + 2]; u.u[3] = pk_[nq][4 * ks + 3];
                }
                Pf[nq] = u.v;
            }
#pragma unroll
            for (int md = 0; md < 2; ++md) {
                s16x8 Vh = *(const s16x8*)(vbase_h + (long)(32 * md + lq) * 2048 + kt + ks * 16 + hi * 8);
                s16x8 Vl = *(const s16x8*)(vbase_l + (long)(32 * md + lq) * 2048 + kt + ks * 16 + hi * 8);
#pragma unroll
                for (int nq = 0; nq < 2; ++nq) {
                    Oa[md][nq] = __builtin_amdgcn_mfma_f32_32x32x16_bf16(Vh, Pf[nq], Oa[md][nq], 0, 0, 0);
                    Oa[md][nq] = __builtin_amdgcn_mfma_f32_32x32x16_bf16(Vl, Pf[nq], Oa[md][nq], 0, 0, 0);
                }
            }
        }
    }

    // stash per-wave partials
#pragma unroll
    for (int md = 0; md < 2; ++md)
#pragma unroll
        for (int nq = 0; nq < 2; ++nq)
#pragma unroll
            for (int r = 0; r < 16; ++r) {
                int d = 32 * md + (r & 3) + 8 * (r >> 2) + 4 * hi;
                Obuf[w][d][nq * 32 + lq] = Oa[md][nq][r];
            }
    if (l < 32) {
        mlbuf[w][0][lq] = m_run[0];
        mlbuf[w][1][lq] = m_run[1];
        mlbuf[w][2][lq] = l_run[0];
        mlbuf[w][3][lq] = l_run[1];
    }
    __syncthreads();

    // combine across waves: thread -> (q = tid&63, d-chunk = tid>>6)
    {
        const int q  = tid & 63;
        const int dc = tid >> 6;
        const int qh = q >> 5, qlo = q & 31;
        float mw[4], lw[4];
#pragma unroll
        for (int w2 = 0; w2 < 4; ++w2) {
            mw[w2] = mlbuf[w2][qh][qlo];
            lw[w2] = mlbuf[w2][2 + qh][qlo];
        }
        float ms = fmaxf(fmaxf(mw[0], mw[1]), fmaxf(mw[2], mw[3]));
        float fw[4], Ls = 0.f;
#pragma unroll
        for (int w2 = 0; w2 < 4; ++w2) { fw[w2] = __expf(mw[w2] - ms); Ls += lw[w2] * fw[w2]; }
        float inv = 1.f / Ls;
        float ov[16];
#pragma unroll
        for (int dd = 0; dd < 16; ++dd) {
            int d = dc * 16 + dd;
            float a = Obuf[0][d][q] * fw[0] + Obuf[1][d][q] * fw[1] +
                      Obuf[2][d][q] * fw[2] + Obuf[3][d][q] * fw[3];
            ov[dd] = a * inv;
        }
        float* dst = o + ((long)(b * LQ + q0 + q)) * DM + h * DK + dc * 16;
        *(float4*)(dst + 0)  = *(float4*)&ov[0];
        *(float4*)(dst + 4)  = *(float4*)&ov[4];
        *(float4*)(dst + 8)  = *(float4*)&ov[8];
        *(float4*)(dst + 12) = *(float4*)&ov[12];
    }
}

// ---------------------------------------------------------------------------
// LayerNorm over last dim (512). One wave per row; 8 floats per lane.
// ---------------------------------------------------------------------------
__global__ __launch_bounds__(256) void ln_kernel(const float* __restrict__ x,
                                                 const float* __restrict__ gamma,
                                                 const float* __restrict__ beta,
                                                 float* __restrict__ out)
{
    const int wave = threadIdx.x >> 6;
    const int lane = threadIdx.x & 63;
    const long row = (long)blockIdx.x * 4 + wave;
    const float* xr = x + row * DM + lane * 8;
    float4 a = *(const float4*)xr;
    float4 b = *(const float4*)(xr + 4);
    float sum = a.x + a.y + a.z + a.w + b.x + b.y + b.z + b.w;
    float sq  = a.x * a.x + a.y * a.y + a.z * a.z + a.w * a.w +
                b.x * b.x + b.y * b.y + b.z * b.z + b.w * b.w;
#pragma unroll
    for (int m = 1; m < 64; m <<= 1) {
        sum += __shfl_xor(sum, m);
        sq  += __shfl_xor(sq, m);
    }
    const float mu  = sum * (1.f / 512.f);
    const float var = sq * (1.f / 512.f) - mu * mu;
    const float rs  = 1.0f / sqrtf(var + LN_EPS);

    float4 g0 = *(const float4*)(gamma + lane * 8);
    float4 g1 = *(const float4*)(gamma + lane * 8 + 4);
    float4 t0 = *(const float4*)(beta + lane * 8);
    float4 t1 = *(const float4*)(beta + lane * 8 + 4);
    float4 o0 = make_float4((a.x - mu) * rs * g0.x + t0.x,
                            (a.y - mu) * rs * g0.y + t0.y,
                            (a.z - mu) * rs * g0.z + t0.z,
                            (a.w - mu) * rs * g0.w + t0.w);
    float4 o1 = make_float4((b.x - mu) * rs * g1.x + t1.x,
                            (b.y - mu) * rs * g1.y + t1.y,
                            (b.z - mu) * rs * g1.z + t1.z,
                            (b.w - mu) * rs * g1.w + t1.w);
    *(float4*)(out + row * DM + lane * 8) = o0;
    *(float4*)(out + row * DM + lane * 8 + 4) = o1;
}

// ---------------------------------------------------------------------------
extern "C" void kernel_launch(void* const* d_in, const int* in_sizes, int n_in,
                              void* d_out, int out_size, void* d_ws, size_t ws_size,
                              hipStream_t stream)
{
    const float* Q    = (const float*)d_in[0];
    const float* K    = (const float*)d_in[1];
    const float* V    = (const float*)d_in[2];
    // d_in[3] = node_num (unused; Lk fixed at 2048)
    const int*   mask = (const int*)d_in[4];
    const float* Wq   = (const float*)d_in[5];
    const float* bq   = (const float*)d_in[6];
    const float* Wk   = (const float*)d_in[7];
    const float* bk   = (const float*)d_in[8];
    const float* Wv   = (const float*)d_in[9];
    const float* bv   = (const float*)d_in[10];
    const float* Wo   = (const float*)d_in[11];
    const float* bo   = (const float*)d_in[12];
    const float* gamma= (const float*)d_in[13];
    const float* beta = (const float*)d_in[14];
    float* out = (float*)d_out;

    char* base = (char*)d_ws;
    float* qp  = (float*)(base);                             // 8 MB (4096x512 f32)
    short* kbh = (short*)(base + (size_t)8  * 1024 * 1024);  // 8 MB
    short* kbl = (short*)(base + (size_t)16 * 1024 * 1024);  // 8 MB
    short* vth = (short*)(base + (size_t)24 * 1024 * 1024);  // 8 MB
    short* vtl = (short*)(base + (size_t)32 * 1024 * 1024);  // 8 MB
    float* ao  = (float*)(base + (size_t)40 * 1024 * 1024);  // 8 MB
    float* tmp = (float*)(base + (size_t)48 * 1024 * 1024);  // 8 MB

    qkv_kernel<<<640, 256, 0, stream>>>(Q, K, V, Wq, bq, Wk, bk, Wv, bv,
                                        qp, kbh, kbl, vth, vtl);
    attn_kernel<<<512, 256, 0, stream>>>(qp, kbh, kbl, vth, vtl, mask, ao);
    ogemm_kernel<<<128, 256, 0, stream>>>(ao, Wo, bo, Q, tmp);
    ln_kernel<<<1024, 256, 0, stream>>>(tmp, gamma, beta, out);
}